// Round 15
// baseline (1824.800 us; speedup 1.0000x reference)
//
#include <hip/hip_runtime.h>
#include <hip/hip_bf16.h>

#define NV 50000
#define NL 100000
#define NC 210000
#define NNZE 630000
#define F 80

// unfused MFMA GEMM tile (V-MLP)
#define TBM 192
#define TBN 80
#define TBK 32
#define LDA 40   // padded LDS row stride in shorts

// fused MLP tile
#define FBM 128  // 4 waves x 32 rows (2 m-frags); Hs-only LDS ~55KB -> 2 blocks/CU
#define CH 80    // H-column chunk (stage-2 K chunk)
#define LDH 104  // Hs row stride in shorts (208 B, 16B-aligned, ~2-way banks)

typedef unsigned short us;
typedef __attribute__((ext_vector_type(8))) short s8v;
typedef __attribute__((ext_vector_type(4))) float f4v;
typedef __attribute__((ext_vector_type(4))) unsigned short us4;
typedef __attribute__((ext_vector_type(8))) unsigned short us8;

__device__ inline us bf16_hi(float x) {
    return (us)(__builtin_bit_cast(unsigned int, x) >> 16);
}
__device__ inline float b2f(us h) {
    return __builtin_bit_cast(float, (unsigned int)h << 16);
}

// ---------------- offsets from sorted edge_clause ----------------
__global__ void build_off(const int* __restrict__ ec, int* __restrict__ off,
                          int nnz, int nc) {
    int e = blockIdx.x * 256 + threadIdx.x;
    if (e >= nnz) return;
    int c = ec[e];
    if (e == 0) {
        for (int cc = 0; cc <= c; ++cc) off[cc] = 0;
    } else {
        int cp = ec[e - 1];
        for (int cc = cp + 1; cc <= c; ++cc) off[cc] = e;
    }
    if (e == nnz - 1) {
        for (int cc = c + 1; cc <= nc; ++cc) off[cc] = nnz;
    }
}

// ---------------- fills ----------------
__global__ void fill_val(float* __restrict__ p, int n, const float* __restrict__ v) {
    int i = blockIdx.x * 256 + threadIdx.x;
    if (i < n) p[i] = v[0];
}
__global__ void zero_int(int* __restrict__ p, int n) {
    int i = blockIdx.x * 256 + threadIdx.x;
    if (i < n) p[i] = 0;
}

// ---------------- lit-CSR build (hist -> 3-stage scan -> scatter -> sort) ----
__global__ void hist_lit(const int* __restrict__ el, int* __restrict__ cnt) {
    int e = blockIdx.x * 256 + threadIdx.x;
    if (e < NNZE) atomicAdd(&cnt[el[e]], 1);
}

__global__ __launch_bounds__(256)
void scan1(const int* __restrict__ cnt, int* __restrict__ bsum, int n) {
    __shared__ int sd[256];
    int i = blockIdx.x * 256 + threadIdx.x;
    sd[threadIdx.x] = (i < n) ? cnt[i] : 0;
    __syncthreads();
    for (int k = 128; k; k >>= 1) {
        if (threadIdx.x < k) sd[threadIdx.x] += sd[threadIdx.x + k];
        __syncthreads();
    }
    if (threadIdx.x == 0) bsum[blockIdx.x] = sd[0];
}

__global__ __launch_bounds__(512)
void scan2(int* __restrict__ bsum, int nb) {   // inclusive scan, nb <= 512
    __shared__ int sd[512];
    int t = threadIdx.x;
    sd[t] = (t < nb) ? bsum[t] : 0;
    __syncthreads();
    for (int off = 1; off < 512; off <<= 1) {
        int v = (t >= off) ? sd[t - off] : 0;
        __syncthreads();
        sd[t] += v;
        __syncthreads();
    }
    if (t < nb) bsum[t] = sd[t];
}

__global__ __launch_bounds__(256)
void scan3(const int* __restrict__ cnt, const int* __restrict__ bsum,
           int* __restrict__ loff, int n) {
    __shared__ int sd[256];
    int t = threadIdx.x;
    int i = blockIdx.x * 256 + t;
    int v = (i < n) ? cnt[i] : 0;
    sd[t] = v;
    __syncthreads();
    for (int off = 1; off < 256; off <<= 1) {
        int u = (t >= off) ? sd[t - off] : 0;
        __syncthreads();
        sd[t] += u;
        __syncthreads();
    }
    int base = blockIdx.x ? bsum[blockIdx.x - 1] : 0;
    if (i < n) loff[i] = base + sd[t] - v;          // exclusive
    if (i == n - 1) loff[n] = base + sd[t];         // total
}

__global__ void scatter_lit(const int* __restrict__ el, const int* __restrict__ ec,
                            const int* __restrict__ loff, int* __restrict__ cur,
                            int* __restrict__ litc) {
    int e = blockIdx.x * 256 + threadIdx.x;
    if (e >= NNZE) return;
    int l = el[e];
    int pos = loff[l] + atomicAdd(&cur[l], 1);
    litc[pos] = ec[e];
}

// deterministic litc content regardless of atomic ordering
__global__ void seg_sort(const int* __restrict__ loff, int* __restrict__ litc) {
    int l = blockIdx.x * 256 + threadIdx.x;
    if (l >= NL) return;
    int a = loff[l], b = loff[l + 1];
    for (int i = a + 1; i < b; ++i) {
        int key = litc[i];
        int j = i - 1;
        while (j >= a && litc[j] > key) { litc[j + 1] = litc[j]; --j; }
        litc[j + 1] = key;
    }
}

// ---------------- weight pre-split: W[K][N] fp32 -> Wh/Wl[N][K] bf16 ----------------
__global__ void split_w(const float* __restrict__ W, int K, int N,
                        us* __restrict__ Wh, us* __restrict__ Wl) {
    int idx = blockIdx.x * 256 + threadIdx.x;
    if (idx >= K * N) return;
    int k = idx / N, n = idx % N;
    float x = W[idx];
    us h = bf16_hi(x);
    Wh[(size_t)n * K + k] = h;
    Wl[(size_t)n * K + k] = bf16_hi(x - b2f(h));
}

// ---------------- LC gather: per (clause, 4-feature), fp32 ----------------
__global__ void lc_gather(const float* __restrict__ L, const int* __restrict__ el,
                          const int* __restrict__ off, const float* __restrict__ scale,
                          float* __restrict__ LC) {
    int idx = blockIdx.x * 256 + threadIdx.x;
    if (idx >= NC * 20) return;
    int c = idx / 20, f4 = idx % 20;
    int e0 = off[c], e1 = off[c + 1];
    float4 s = make_float4(0.f, 0.f, 0.f, 0.f);
    for (int e = e0; e < e1; ++e) {
        const float4 v = *(const float4*)&L[(size_t)el[e] * F + f4 * 4];
        s.x += v.x; s.y += v.y; s.z += v.z; s.w += v.w;
    }
    float sc = scale[0];
    s.x *= sc; s.y *= sc; s.z *= sc; s.w *= sc;
    *(float4*)&LC[(size_t)c * F + f4 * 4] = s;
}

// ---------------- CL gather over RAW C with fused affine normalization --------------
__global__ void cl_gather(const float* __restrict__ C, const int* __restrict__ loff,
                          const int* __restrict__ litc, const float* __restrict__ scale,
                          const float* __restrict__ statsC, float* __restrict__ CL) {
    int idx = blockIdx.x * 256 + threadIdx.x;
    if (idx >= NL * 20) return;
    int lit = idx / 20, f4 = idx % 20;
    int e0 = loff[lit], e1 = loff[lit + 1];
    float4 s = make_float4(0.f, 0.f, 0.f, 0.f);
    for (int e = e0; e < e1; ++e) {
        const float4 v = *(const float4*)&C[(size_t)litc[e] * F + f4 * 4];
        s.x += v.x; s.y += v.y; s.z += v.z; s.w += v.w;
    }
    float sc = scale[0];
    float cnt = (float)(e1 - e0);
    float r[4] = {s.x, s.y, s.z, s.w};
    float4 o;
#pragma unroll
    for (int j = 0; j < 4; ++j) {
        int col = f4 * 4 + j;
        float m = statsC[col], rs = statsC[80 + col];
        r[j] = (r[j] - cnt * m) * rs * sc;
    }
    o.x = r[0]; o.y = r[1]; o.z = r[2]; o.w = r[3];
    *(float4*)&CL[(size_t)lit * F + f4 * 4] = o;
}

// =====================================================================
// FUSED 2-layer MLP: Out = (relu6(A @ W1 + b1)) @ W2 + b2   (N2 = 80)
// BARRIER-FREE main loop: A fragments are read per-lane directly from
// global (zero intra-wave redundancy — each row's 32B/K-step read once),
// W1/W2 fragments per-lane from pre-split planes (L2-hot), and Hs rows
// are WAVE-PRIVATE (written and read by the same wave; same-wave LDS
// ordering via lgkmcnt). Only the init sync and the stats-epilogue sync
// remain. Values and op order identical to the staged version.
// =====================================================================
__global__ __launch_bounds__(256, 2)
void mlp_fused(const float* __restrict__ A0, const float* __restrict__ A1,
               const float* __restrict__ A2, int pw, int flip2, int rbase,
               int M, int K1, int N1,
               const us* __restrict__ W1h, const us* __restrict__ W1l,
               const float* __restrict__ b1,
               const us* __restrict__ W2h, const us* __restrict__ W2l,
               const float* __restrict__ b2,
               float* __restrict__ Out, const float* __restrict__ nstat,
               float* __restrict__ Psum, float* __restrict__ Psq) {
    __shared__ __align__(16) us HsH[FBM * LDH];
    __shared__ __align__(16) us HsL[FBM * LDH];
    __shared__ float ns[160];
    __shared__ float bs1[240];
    __shared__ float csum[80], csq[80];

    const int t = threadIdx.x;
    const int m0 = blockIdx.x * FBM;
    const int w = t >> 6;
    const int l = t & 63;
    const int lr = l & 15;
    const int lk = (l >> 4) * 8;

    if (nstat && t < 160) ns[t] = nstat[t];
    if (t < N1) bs1[t] = b1[t];
    if (t < 80) { csum[t] = 0.f; csq[t] = 0.f; }
    // zero the Hs pad region (cols [CH..CH+16)) once
    for (int u = t; u < FBM * 4; u += 256) {
        int row = u >> 2, cq = u & 3;
        us4 z = {0, 0, 0, 0};
        *(us4*)&HsH[row * LDH + CH + cq * 4] = z;
        *(us4*)&HsL[row * LDH + CH + cq * 4] = z;
    }
    __syncthreads();

    f4v acc2[2][5];
#pragma unroll
    for (int i = 0; i < 2; ++i)
#pragma unroll
        for (int j = 0; j < 5; ++j) acc2[i][j] = (f4v)0.f;

    const int nk1 = (K1 + TBK - 1) / TBK;

    for (int c2 = 0; c2 < N1; c2 += CH) {
        // ---------- stage 1: H chunk [FBM x 80], swapped-operand MFMA ----------
        f4v acc1[5][2];   // [n1-frag][m-frag]
#pragma unroll
        for (int i = 0; i < 5; ++i)
#pragma unroll
            for (int j = 0; j < 2; ++j) acc1[i][j] = (f4v)0.f;

        for (int s = 0; s < nk1; ++s) {
            const int kg = s * TBK + lk;
            const bool kv = kg < K1;

            // A fragments: per-lane direct global load + hi/lo split
            s8v aH[2], aL[2];
#pragma unroll
            for (int mf = 0; mf < 2; ++mf) {
                s8v h8 = {0, 0, 0, 0, 0, 0, 0, 0};
                s8v l8 = {0, 0, 0, 0, 0, 0, 0, 0};
                int row = m0 + w * 32 + mf * 16 + lr;
                if (kv && row < M) {
                    int piece = (kg >= pw) + (kg >= 2 * pw);
                    int kk = kg - piece * pw;
                    const float* P = piece == 0 ? A0 : piece == 1 ? A1 : A2;
                    int re = row;
                    if (piece == 2 && flip2) {
                        int g = rbase + row;
                        re = (g < NV) ? g + NV : g - NV;
                    }
                    const float* src = P + (size_t)re * pw + kk;
                    float4 v0 = *(const float4*)src;
                    float4 v1 = *(const float4*)(src + 4);
                    float f0[8] = {v0.x, v0.y, v0.z, v0.w, v1.x, v1.y, v1.z, v1.w};
                    if (piece == 0 && nstat) {
#pragma unroll
                        for (int j = 0; j < 8; ++j)
                            f0[j] = (f0[j] - ns[kk + j]) * ns[80 + kk + j];
                    }
#pragma unroll
                    for (int j = 0; j < 8; ++j) {
                        us h = bf16_hi(f0[j]);
                        h8[j] = (short)h;
                        l8[j] = (short)bf16_hi(f0[j] - b2f(h));
                    }
                }
                aH[mf] = h8; aL[mf] = l8;
            }
            // W1 fragments: per-lane direct global (L2-hot)
            s8v wH[5], wL[5];
#pragma unroll
            for (int nf = 0; nf < 5; ++nf) {
                int br = c2 + nf * 16 + lr;
                s8v z = {0, 0, 0, 0, 0, 0, 0, 0};
                wH[nf] = kv ? *(const s8v*)&W1h[(size_t)br * K1 + kg] : z;
                wL[nf] = kv ? *(const s8v*)&W1l[(size_t)br * K1 + kg] : z;
            }
            // swapped operands: W-frag first (-> D row = n1), A-frag second (-> D col = m)
#pragma unroll
            for (int nf = 0; nf < 5; ++nf)
#pragma unroll
                for (int mf = 0; mf < 2; ++mf) {
                    acc1[nf][mf] = __builtin_amdgcn_mfma_f32_16x16x32_bf16(wH[nf], aH[mf], acc1[nf][mf], 0, 0, 0);
                    acc1[nf][mf] = __builtin_amdgcn_mfma_f32_16x16x32_bf16(wL[nf], aH[mf], acc1[nf][mf], 0, 0, 0);
                    acc1[nf][mf] = __builtin_amdgcn_mfma_f32_16x16x32_bf16(wH[nf], aL[mf], acc1[nf][mf], 0, 0, 0);
                }
        }

        // ---------- stage-1 epilogue: bias1 + relu6, split, pack -> wave-private Hs ----
#pragma unroll
        for (int nf = 0; nf < 5; ++nf) {
            int n1b = nf * 16 + ((l >> 4) << 2);
#pragma unroll
            for (int mf = 0; mf < 2; ++mf) {
                int m = w * 32 + mf * 16 + lr;
                us4 hv, lv;
#pragma unroll
                for (int r = 0; r < 4; ++r) {
                    float v = acc1[nf][mf][r] + bs1[c2 + n1b + r];
                    v = fminf(fmaxf(v, 0.f), 6.f);
                    us h = bf16_hi(v);
                    hv[r] = h;
                    lv[r] = bf16_hi(v - b2f(h));
                }
                *(us4*)&HsH[m * LDH + n1b] = hv;
                *(us4*)&HsL[m * LDH + n1b] = lv;
            }
        }
        // no barrier: Hs rows are wave-private (same-wave LDS ordering)

        // ---------- stage 2: acc2 += H_chunk @ W2[c2..c2+80, :] ----------
#pragma unroll
        for (int ks = 0; ks < 3; ++ks) {
            int klocal = ks * 32 + lk;
            s8v a2H[2], a2L[2], b2H[5], b2L[5];
#pragma unroll
            for (int mf = 0; mf < 2; ++mf) {
                int ar = w * 32 + mf * 16 + lr;
                a2H[mf] = *(const s8v*)&HsH[ar * LDH + klocal];
                a2L[mf] = *(const s8v*)&HsL[ar * LDH + klocal];
            }
            bool bval = klocal < CH;
            int kg = c2 + klocal;
#pragma unroll
            for (int nf = 0; nf < 5; ++nf) {
                int n2 = nf * 16 + lr;
                s8v z = {0, 0, 0, 0, 0, 0, 0, 0};
                b2H[nf] = bval ? *(const s8v*)&W2h[(size_t)n2 * N1 + kg] : z;
                b2L[nf] = bval ? *(const s8v*)&W2l[(size_t)n2 * N1 + kg] : z;
            }
#pragma unroll
            for (int mf = 0; mf < 2; ++mf)
#pragma unroll
                for (int nf = 0; nf < 5; ++nf) {
                    acc2[mf][nf] = __builtin_amdgcn_mfma_f32_16x16x32_bf16(a2H[mf], b2H[nf], acc2[mf][nf], 0, 0, 0);
                    acc2[mf][nf] = __builtin_amdgcn_mfma_f32_16x16x32_bf16(a2L[mf], b2H[nf], acc2[mf][nf], 0, 0, 0);
                    acc2[mf][nf] = __builtin_amdgcn_mfma_f32_16x16x32_bf16(a2H[mf], b2L[nf], acc2[mf][nf], 0, 0, 0);
                }
        }
        // no barrier: next chunk overwrites only this wave's own Hs rows
    }

    // ---------- final epilogue: bias2, store, fused column stats ----------
#pragma unroll
    for (int nf = 0; nf < 5; ++nf) {
        int col = nf * 16 + lr;
        float bv = b2[col];
        float ls = 0.f, lq = 0.f;
#pragma unroll
        for (int mf = 0; mf < 2; ++mf) {
            int rowb = m0 + w * 32 + mf * 16 + (l >> 4) * 4;
#pragma unroll
            for (int r = 0; r < 4; ++r) {
                int row = rowb + r;
                if (row < M) {
                    float v = acc2[mf][nf][r] + bv;
                    Out[(size_t)row * 80 + col] = v;
                    ls += v; lq += v * v;
                }
            }
        }
        ls += __shfl_xor(ls, 16); ls += __shfl_xor(ls, 32);
        lq += __shfl_xor(lq, 16); lq += __shfl_xor(lq, 32);
        if (l < 16) {
            atomicAdd(&csum[col], ls);
            atomicAdd(&csq[col], lq);
        }
    }
    __syncthreads();
    if (t < 80) {
        size_t pb = (size_t)blockIdx.x * 80 + t;
        Psum[pb] = csum[t];
        Psq[pb] = csq[t];
    }
}

// ---------------- unfused MFMA GEMM (V-MLP) ----------------
__global__ __launch_bounds__(256, 3)
void gemm_mfma(const float* __restrict__ A0, const float* __restrict__ A1,
               const float* __restrict__ A2, int pw, int flip2, int rbase,
               int M, int K, int N,
               const us* __restrict__ Wh, const us* __restrict__ Wl,
               const float* __restrict__ bias, float* __restrict__ Out, int act) {
    __shared__ __align__(16) us AsH[TBM * LDA];
    __shared__ __align__(16) us AsL[TBM * LDA];
    __shared__ __align__(16) us BsH[TBN * LDA];
    __shared__ __align__(16) us BsL[TBN * LDA];

    const int t = threadIdx.x;
    const int m0 = blockIdx.x * TBM;
    const int n0 = blockIdx.y * TBN;
    const int w = t >> 6;
    const int l = t & 63;
    const int lr = l & 15;
    const int lk = (l >> 4) * 8;
    const int q = t & 3;
    const int rb = t >> 2;

    f4v acc[3][5];
#pragma unroll
    for (int i = 0; i < 3; ++i)
#pragma unroll
        for (int j = 0; j < 5; ++j) acc[i][j] = (f4v)0.f;

    float4 pa[3][2];

#define ALOAD(K0)                                                              \
    {                                                                          \
        _Pragma("unroll")                                                      \
        for (int i = 0; i < 3; ++i) {                                          \
            int row = m0 + i * 64 + rb;                                        \
            int kg = (K0) + q * 8;                                             \
            float4 z = make_float4(0.f, 0.f, 0.f, 0.f);                        \
            pa[i][0] = z; pa[i][1] = z;                                        \
            if (row < M && kg < K) {                                           \
                int piece = (kg >= pw) + (kg >= 2 * pw);                       \
                int kk = kg - piece * pw;                                      \
                const float* P = piece == 0 ? A0 : piece == 1 ? A1 : A2;       \
                int re = row;                                                  \
                if (piece == 2 && flip2) {                                     \
                    int g = rbase + row;                                       \
                    re = (g < NV) ? g + NV : g - NV;                           \
                }                                                              \
                const float* src = P + (size_t)re * pw + kk;                   \
                pa[i][0] = *(const float4*)src;                                \
                pa[i][1] = *(const float4*)(src + 4);                          \
            }                                                                  \
        }                                                                      \
    }

    const int nk = (K + TBK - 1) / TBK;
    ALOAD(0);

    for (int s = 0; s < nk; ++s) {
        const int k0 = s * TBK;
#pragma unroll
        for (int i = 0; i < 3; ++i) {
            float f0[8] = {pa[i][0].x, pa[i][0].y, pa[i][0].z, pa[i][0].w,
                           pa[i][1].x, pa[i][1].y, pa[i][1].z, pa[i][1].w};
            us8 hv, lv;
#pragma unroll
            for (int j = 0; j < 8; ++j) {
                us h = bf16_hi(f0[j]);
                hv[j] = h;
                lv[j] = bf16_hi(f0[j] - b2f(h));
            }
            int r = i * 64 + rb;
            *(us8*)&AsH[r * LDA + q * 8] = hv;
            *(us8*)&AsL[r * LDA + q * 8] = lv;
        }
#pragma unroll
        for (int i = 0; i < 3; ++i) {
            int u = i * 256 + t;
            if (u < 640) {
                int hi = (u < 320);
                int c = hi ? u : u - 320;
                int n = c >> 2, cq = c & 3;
                int kg = k0 + cq * 8;
                us8 v = {0, 0, 0, 0, 0, 0, 0, 0};
                if (kg < K)
                    v = *(const us8*)&(hi ? Wh : Wl)[(size_t)(n0 + n) * K + kg];
                *(us8*)&(hi ? BsH : BsL)[n * LDA + cq * 8] = v;
            }
        }
        __syncthreads();

        s8v aH[3], aL[3], bH[5], bL[5];
#pragma unroll
        for (int mf = 0; mf < 3; ++mf) {
            int ar = w * 48 + mf * 16 + lr;
            aH[mf] = *(const s8v*)&AsH[ar * LDA + lk];
            aL[mf] = *(const s8v*)&AsL[ar * LDA + lk];
        }
#pragma unroll
        for (int nf = 0; nf < 5; ++nf) {
            int br = nf * 16 + lr;
            bH[nf] = *(const s8v*)&BsH[br * LDA + lk];
            bL[nf] = *(const s8v*)&BsL[br * LDA + lk];
        }
        if (s + 1 < nk) ALOAD(k0 + TBK);
#pragma unroll
        for (int mf = 0; mf < 3; ++mf)
#pragma unroll
            for (int nf = 0; nf < 5; ++nf) {
                acc[mf][nf] = __builtin_amdgcn_mfma_f32_16x16x32_bf16(aH[mf], bH[nf], acc[mf][nf], 0, 0, 0);
                acc[mf][nf] = __builtin_amdgcn_mfma_f32_16x16x32_bf16(aL[mf], bH[nf], acc[mf][nf], 0, 0, 0);
                acc[mf][nf] = __builtin_amdgcn_mfma_f32_16x16x32_bf16(aH[mf], bL[nf], acc[mf][nf], 0, 0, 0);
            }
        __syncthreads();
    }
#undef ALOAD

#pragma unroll
    for (int mf = 0; mf < 3; ++mf) {
        int rowb = m0 + w * 48 + mf * 16 + (l >> 4) * 4;
#pragma unroll
        for (int nf = 0; nf < 5; ++nf) {
            int col = n0 + nf * 16 + lr;
            float bv = bias[col];
#pragma unroll
            for (int r = 0; r < 4; ++r) {
                int row = rowb + r;
                if (row < M) {
                    float v = acc[mf][nf][r] + bv;
                    if (act) v = fminf(fmaxf(v, 0.f), 6.f);
                    Out[(size_t)row * N + col] = v;
                }
            }
        }
    }
}

// ---------------- stats finalize: one block per column ----------------
__global__ __launch_bounds__(256)
void colstats_final(const float* __restrict__ Psum, const float* __restrict__ Psq,
                    int nblk, int M, float* __restrict__ stats) {
    __shared__ float sd[256], qd[256];
    int c = blockIdx.x;
    int tid = threadIdx.x;
    float s = 0.f, q = 0.f;
    for (int b = tid; b < nblk; b += 256) {
        s += Psum[(size_t)b * 80 + c];
        q += Psq [(size_t)b * 80 + c];
    }
    sd[tid] = s; qd[tid] = q;
    __syncthreads();
    for (int k = 128; k; k >>= 1) {
        if (tid < k) { sd[tid] += sd[tid + k]; qd[tid] += qd[tid + k]; }
        __syncthreads();
    }
    if (tid == 0) {
        float mean = sd[0] / (float)M;
        float var = qd[0] / (float)M - mean * mean;
        if (var < 0.f) var = 0.f;
        stats[c] = mean;
        stats[80 + c] = rsqrtf(var + 1e-3f);
    }
}

__global__ void norm_apply(float* __restrict__ X, int M, const float* __restrict__ stats) {
    int idx = blockIdx.x * 256 + threadIdx.x;
    if (idx >= M * F) return;
    int c = idx % F;
    X[idx] = (X[idx] - stats[c]) * stats[80 + c];
}

// ---------------- final V layer ----------------
__global__ __launch_bounds__(256)
void vscore_kernel(const float* __restrict__ H, const float* __restrict__ w,
                   const float* __restrict__ b, float* __restrict__ out, int M) {
    int wid = (blockIdx.x * 256 + threadIdx.x) / 64;
    int lane = threadIdx.x % 64;
    if (wid >= M) return;
    const float* row = H + (size_t)wid * 160;
    float s = 0.f;
    for (int c = lane; c < 160; c += 64) s += row[c] * w[c];
    for (int off = 32; off; off >>= 1) s += __shfl_down(s, off);
    if (lane == 0) out[wid] = s + b[0];
}

// ---------------- loss ----------------
__global__ __launch_bounds__(256)
void loss_clause(const int* __restrict__ el, const int* __restrict__ off,
                 const float* __restrict__ scores, float* __restrict__ partial, int nc) {
    __shared__ float sd[256];
    int c = blockIdx.x * 256 + threadIdx.x;
    float term = 0.f;
    if (c < nc) {
        int e0 = off[c], e1 = off[c + 1];
        float cs = 0.f;
        for (int e = e0; e < e1; ++e) {
            int lit = el[e];
            float v = (lit < NV) ? scores[lit] : -scores[lit - NV];
            cs += fmaxf(v, 0.f) + log1pf(expf(-fabsf(v)));
        }
        float cv = expf(-cs);
        term = cv * (-logf(1.0f - cv + 1e-8f));
    }
    sd[threadIdx.x] = term;
    __syncthreads();
    for (int s = 128; s; s >>= 1) {
        if (threadIdx.x < s) sd[threadIdx.x] += sd[threadIdx.x + s];
        __syncthreads();
    }
    if (threadIdx.x == 0) partial[blockIdx.x] = sd[0];
}

__global__ void loss_final(const float* __restrict__ partial, int n, float* __restrict__ out) {
    __shared__ float sd[256];
    float s = 0.f;
    for (int i = threadIdx.x; i < n; i += 256) s += partial[i];
    sd[threadIdx.x] = s;
    __syncthreads();
    for (int k = 128; k; k >>= 1) {
        if (threadIdx.x < k) sd[threadIdx.x] += sd[threadIdx.x + k];
        __syncthreads();
    }
    if (threadIdx.x == 0) out[0] = sd[0];
}

// =======================================================================
static inline size_t alignup(size_t x) { return (x + 255) & ~(size_t)255; }

extern "C" void kernel_launch(void* const* d_in, const int* in_sizes, int n_in,
                              void* d_out, int out_size, void* d_ws, size_t ws_size,
                              hipStream_t stream) {
    const int*   el   = (const int*)d_in[0];
    const int*   ec   = (const int*)d_in[1];
    const float* l_init = (const float*)d_in[4];
    const float* c_init = (const float*)d_in[5];
    const float* lc_s = (const float*)d_in[6];
    const float* cl_s = (const float*)d_in[7];
    const float* Cw1 = (const float*)d_in[8],  *Cb1 = (const float*)d_in[9];
    const float* Cw2 = (const float*)d_in[10], *Cb2 = (const float*)d_in[11];
    const float* Lw1 = (const float*)d_in[12], *Lb1 = (const float*)d_in[13];
    const float* Lw2 = (const float*)d_in[14], *Lb2 = (const float*)d_in[15];
    const float* Vw1 = (const float*)d_in[16], *Vb1 = (const float*)d_in[17];
    const float* Vw2 = (const float*)d_in[18], *Vb2 = (const float*)d_in[19];
    const float* Vw3 = (const float*)d_in[20], *Vb3 = (const float*)d_in[21];
    const float* Vw4 = (const float*)d_in[22], *Vb4 = (const float*)d_in[23];
    float* out = (float*)d_out;

    // ---- workspace carve-up ----
    char* p = (char*)d_ws;
    size_t o = 0;
    int* off  = (int*)(p + o); o += alignup((size_t)(NC + 1) * 4);
    int* loff = (int*)(p + o); o += alignup((size_t)(NL + 1) * 4);
    int* lcnt = (int*)(p + o); o += alignup((size_t)NL * 4);
    int* lcur = (int*)(p + o); o += alignup((size_t)NL * 4);
    int* bsum = (int*)(p + o); o += alignup((size_t)512 * 4);
    int* litc = (int*)(p + o); o += alignup((size_t)NNZE * 4);
    float* L0  = (float*)(p + o); o += alignup((size_t)NL * F * 4);
    float* L1  = (float*)(p + o); o += alignup((size_t)NL * F * 4);
    float* Cb  = (float*)(p + o); o += alignup((size_t)NC * F * 4);
    float* MSG = (float*)(p + o); o += alignup((size_t)NC * F * 4);
    float* H   = (float*)(p + o); o += alignup((size_t)8400000 * 4);
    float* Psum = (float*)(p + o); o += alignup((size_t)2048 * 80 * 4);
    float* Psq  = (float*)(p + o); o += alignup((size_t)2048 * 80 * 4);
    float* statsC = (float*)(p + o); o += alignup(160 * 4);
    float* statsL = (float*)(p + o); o += alignup(160 * 4);
    float* lossP  = (float*)(p + o); o += alignup(1024 * 4);
    us* Wsp = (us*)(p + o); o += alignup((size_t)192000 * 2 * 2);
    us* Cw1h = Wsp,          *Cw1l = Cw1h + 25600;
    us* Cw2h = Cw1l + 25600, *Cw2l = Cw2h + 12800;
    us* Lw1h = Cw2l + 12800, *Lw1l = Lw1h + 57600;
    us* Lw2h = Lw1l + 57600, *Lw2l = Lw2h + 19200;
    us* Vw1h = Lw2l + 19200, *Vw1l = Vw1h + 25600;
    us* Vw2h = Vw1l + 25600, *Vw2l = Vw2h + 25600;
    us* Vw3h = Vw2l + 25600, *Vw3l = Vw3h + 25600;
    (void)ws_size; (void)n_in; (void)in_sizes; (void)out_size;

    // ---- CSR offsets + lit-CSR (parallel scan) ----
    build_off<<<(NNZE + 255) / 256, 256, 0, stream>>>(ec, off, NNZE, NC);
    zero_int<<<(NL + 255) / 256, 256, 0, stream>>>(lcnt, NL);
    zero_int<<<(NL + 255) / 256, 256, 0, stream>>>(lcur, NL);
    hist_lit<<<(NNZE + 255) / 256, 256, 0, stream>>>(el, lcnt);
    const int nb = (NL + 255) / 256;   // 391
    scan1<<<nb, 256, 0, stream>>>(lcnt, bsum, NL);
    scan2<<<1, 512, 0, stream>>>(bsum, nb);
    scan3<<<nb, 256, 0, stream>>>(lcnt, bsum, loff, NL);
    scatter_lit<<<(NNZE + 255) / 256, 256, 0, stream>>>(el, ec, loff, lcur, litc);
    seg_sort<<<(NL + 255) / 256, 256, 0, stream>>>(loff, litc);

    // ---- weight pre-split ----
    split_w<<<(25600 + 255) / 256, 256, 0, stream>>>(Cw1, 160, 160, Cw1h, Cw1l);
    split_w<<<(12800 + 255) / 256, 256, 0, stream>>>(Cw2, 160,  80, Cw2h, Cw2l);
    split_w<<<(57600 + 255) / 256, 256, 0, stream>>>(Lw1, 240, 240, Lw1h, Lw1l);
    split_w<<<(19200 + 255) / 256, 256, 0, stream>>>(Lw2, 240,  80, Lw2h, Lw2l);
    split_w<<<(25600 + 255) / 256, 256, 0, stream>>>(Vw1, 160, 160, Vw1h, Vw1l);
    split_w<<<(25600 + 255) / 256, 256, 0, stream>>>(Vw2, 160, 160, Vw2h, Vw2l);
    split_w<<<(25600 + 255) / 256, 256, 0, stream>>>(Vw3, 160, 160, Vw3h, Vw3l);

    // ---- init L, C (raw) ----
    fill_val<<<(NL * F + 255) / 256, 256, 0, stream>>>(L0, NL * F, l_init);
    fill_val<<<(NC * F + 255) / 256, 256, 0, stream>>>(Cb, NC * F, c_init);

    float* Lc = L0, *Ln = L1;
    const int nblkC = (NC + FBM - 1) / FBM;   // 1641
    const int nblkL = (NL + FBM - 1) / FBM;   // 782

    for (int round = 0; round < 4; ++round) {
        // LC_msgs from normalized L
        float* LC = MSG;
        lc_gather<<<(NC * 20 + 255) / 256, 256, 0, stream>>>(Lc, el, off, lc_s, LC);

        // fused C MLP (in-place on raw Cb; piece-0 norm fused for rounds > 0)
        const float* nsC = (round > 0) ? statsC : nullptr;
        mlp_fused<<<nblkC, 256, 0, stream>>>(Cb, LC, nullptr, 80, 0, 0, NC, 160, 160,
                                             Cw1h, Cw1l, Cb1, Cw2h, Cw2l, Cb2,
                                             Cb, nsC, Psum, Psq);
        colstats_final<<<80, 256, 0, stream>>>(Psum, Psq, nblkC, NC, statsC);

        // CL_msgs from RAW C with fused norm (lit-CSR gather)
        float* CL = MSG;
        cl_gather<<<(NL * 20 + 255) / 256, 256, 0, stream>>>(Cb, loff, litc, cl_s, statsC, CL);

        // fused L MLP (reads normalized Lc incl. flip; writes raw Ln)
        mlp_fused<<<nblkL, 256, 0, stream>>>(Lc, CL, Lc, 80, 1, 0, NL, 240, 240,
                                             Lw1h, Lw1l, Lb1, Lw2h, Lw2l, Lb2,
                                             Ln, nullptr, Psum, Psq);
        colstats_final<<<80, 256, 0, stream>>>(Psum, Psq, nblkL, NL, statsL);
        norm_apply<<<(NL * F + 255) / 256, 256, 0, stream>>>(Ln, NL, statsL);

        float* t = Lc; Lc = Ln; Ln = t;
    }

    // ---- V MLP on normalized L (unfused path) ----
    {
        float* H2 = MSG;
        dim3 g((NV + TBM - 1) / TBM, 2);
        gemm_mfma<<<g, 256, 0, stream>>>(Lc, Lc + (size_t)NV * F, nullptr, 80, 0, 0,
                                         NV, 160, 160, Vw1h, Vw1l, Vb1, H, 1);
        gemm_mfma<<<g, 256, 0, stream>>>(H, nullptr, nullptr, 160, 0, 0,
                                         NV, 160, 160, Vw2h, Vw2l, Vb2, H2, 1);
        gemm_mfma<<<g, 256, 0, stream>>>(H2, nullptr, nullptr, 160, 0, 0,
                                         NV, 160, 160, Vw3h, Vw3l, Vb3, H, 1);
        vscore_kernel<<<(NV * 64 + 255) / 256, 256, 0, stream>>>(H, Vw4, Vb4, out, NV);
    }

    // ---- loss ----
    {
        int nblk = (NC + 255) / 256;
        loss_clause<<<nblk, 256, 0, stream>>>(el, off, out, lossP, NC);
        loss_final<<<1, 256, 0, stream>>>(lossP, nblk, out + NV);
    }
}

// Round 16
// 1783.310 us; speedup vs baseline: 1.0233x; 1.0233x over previous
//
#include <hip/hip_runtime.h>
#include <hip/hip_bf16.h>

#define NV 50000
#define NL 100000
#define NC 210000
#define NNZE 630000
#define F 80

// unfused MFMA GEMM tile (V-MLP)
#define TBM 192
#define TBN 80
#define TBK 32
#define LDA 40   // padded LDS row stride in shorts

// fused MLP tile
#define FBM 128  // 4 waves x 32 rows (2 m-frags); Hs-only LDS ~55KB -> 2 blocks/CU
#define CH 80    // H-column chunk (stage-2 K chunk)
#define LDH 104  // Hs row stride in shorts (208 B, 16B-aligned, ~2-way banks)

typedef unsigned short us;
typedef __attribute__((ext_vector_type(8))) short s8v;
typedef __attribute__((ext_vector_type(4))) float f4v;
typedef __attribute__((ext_vector_type(4))) unsigned short us4;
typedef __attribute__((ext_vector_type(8))) unsigned short us8;

__device__ inline us bf16_hi(float x) {
    return (us)(__builtin_bit_cast(unsigned int, x) >> 16);
}
__device__ inline float b2f(us h) {
    return __builtin_bit_cast(float, (unsigned int)h << 16);
}

// ---------------- offsets from sorted edge_clause ----------------
__global__ void build_off(const int* __restrict__ ec, int* __restrict__ off,
                          int nnz, int nc) {
    int e = blockIdx.x * 256 + threadIdx.x;
    if (e >= nnz) return;
    int c = ec[e];
    if (e == 0) {
        for (int cc = 0; cc <= c; ++cc) off[cc] = 0;
    } else {
        int cp = ec[e - 1];
        for (int cc = cp + 1; cc <= c; ++cc) off[cc] = e;
    }
    if (e == nnz - 1) {
        for (int cc = c + 1; cc <= nc; ++cc) off[cc] = nnz;
    }
}

// ---------------- fills ----------------
__global__ void fill_val(float* __restrict__ p, int n, const float* __restrict__ v) {
    int i = blockIdx.x * 256 + threadIdx.x;
    if (i < n) p[i] = v[0];
}
__global__ void zero_int(int* __restrict__ p, int n) {
    int i = blockIdx.x * 256 + threadIdx.x;
    if (i < n) p[i] = 0;
}

// ---------------- lit-CSR build (hist -> 3-stage scan -> scatter -> sort) ----
__global__ void hist_lit(const int* __restrict__ el, int* __restrict__ cnt) {
    int e = blockIdx.x * 256 + threadIdx.x;
    if (e < NNZE) atomicAdd(&cnt[el[e]], 1);
}

__global__ __launch_bounds__(256)
void scan1(const int* __restrict__ cnt, int* __restrict__ bsum, int n) {
    __shared__ int sd[256];
    int i = blockIdx.x * 256 + threadIdx.x;
    sd[threadIdx.x] = (i < n) ? cnt[i] : 0;
    __syncthreads();
    for (int k = 128; k; k >>= 1) {
        if (threadIdx.x < k) sd[threadIdx.x] += sd[threadIdx.x + k];
        __syncthreads();
    }
    if (threadIdx.x == 0) bsum[blockIdx.x] = sd[0];
}

__global__ __launch_bounds__(512)
void scan2(int* __restrict__ bsum, int nb) {   // inclusive scan, nb <= 512
    __shared__ int sd[512];
    int t = threadIdx.x;
    sd[t] = (t < nb) ? bsum[t] : 0;
    __syncthreads();
    for (int off = 1; off < 512; off <<= 1) {
        int v = (t >= off) ? sd[t - off] : 0;
        __syncthreads();
        sd[t] += v;
        __syncthreads();
    }
    if (t < nb) bsum[t] = sd[t];
}

__global__ __launch_bounds__(256)
void scan3(const int* __restrict__ cnt, const int* __restrict__ bsum,
           int* __restrict__ loff, int n) {
    __shared__ int sd[256];
    int t = threadIdx.x;
    int i = blockIdx.x * 256 + t;
    int v = (i < n) ? cnt[i] : 0;
    sd[t] = v;
    __syncthreads();
    for (int off = 1; off < 256; off <<= 1) {
        int u = (t >= off) ? sd[t - off] : 0;
        __syncthreads();
        sd[t] += u;
        __syncthreads();
    }
    int base = blockIdx.x ? bsum[blockIdx.x - 1] : 0;
    if (i < n) loff[i] = base + sd[t] - v;          // exclusive
    if (i == n - 1) loff[n] = base + sd[t];         // total
}

__global__ void scatter_lit(const int* __restrict__ el, const int* __restrict__ ec,
                            const int* __restrict__ loff, int* __restrict__ cur,
                            int* __restrict__ litc) {
    int e = blockIdx.x * 256 + threadIdx.x;
    if (e >= NNZE) return;
    int l = el[e];
    int pos = loff[l] + atomicAdd(&cur[l], 1);
    litc[pos] = ec[e];
}

// deterministic litc content regardless of atomic ordering
__global__ void seg_sort(const int* __restrict__ loff, int* __restrict__ litc) {
    int l = blockIdx.x * 256 + threadIdx.x;
    if (l >= NL) return;
    int a = loff[l], b = loff[l + 1];
    for (int i = a + 1; i < b; ++i) {
        int key = litc[i];
        int j = i - 1;
        while (j >= a && litc[j] > key) { litc[j + 1] = litc[j]; --j; }
        litc[j + 1] = key;
    }
}

// ---------------- weight pre-split: W[K][N] fp32 -> Wh/Wl[N][K] bf16 ----------------
__global__ void split_w(const float* __restrict__ W, int K, int N,
                        us* __restrict__ Wh, us* __restrict__ Wl) {
    int idx = blockIdx.x * 256 + threadIdx.x;
    if (idx >= K * N) return;
    int k = idx / N, n = idx % N;
    float x = W[idx];
    us h = bf16_hi(x);
    Wh[(size_t)n * K + k] = h;
    Wl[(size_t)n * K + k] = bf16_hi(x - b2f(h));
}

// ---------------- LC gather: per (clause, 4-feature), fp32 ----------------
__global__ void lc_gather(const float* __restrict__ L, const int* __restrict__ el,
                          const int* __restrict__ off, const float* __restrict__ scale,
                          float* __restrict__ LC) {
    int idx = blockIdx.x * 256 + threadIdx.x;
    if (idx >= NC * 20) return;
    int c = idx / 20, f4 = idx % 20;
    int e0 = off[c], e1 = off[c + 1];
    float4 s = make_float4(0.f, 0.f, 0.f, 0.f);
    for (int e = e0; e < e1; ++e) {
        const float4 v = *(const float4*)&L[(size_t)el[e] * F + f4 * 4];
        s.x += v.x; s.y += v.y; s.z += v.z; s.w += v.w;
    }
    float sc = scale[0];
    s.x *= sc; s.y *= sc; s.z *= sc; s.w *= sc;
    *(float4*)&LC[(size_t)c * F + f4 * 4] = s;
}

// ---------------- CL gather over RAW C with fused affine normalization --------------
__global__ void cl_gather(const float* __restrict__ C, const int* __restrict__ loff,
                          const int* __restrict__ litc, const float* __restrict__ scale,
                          const float* __restrict__ statsC, float* __restrict__ CL) {
    int idx = blockIdx.x * 256 + threadIdx.x;
    if (idx >= NL * 20) return;
    int lit = idx / 20, f4 = idx % 20;
    int e0 = loff[lit], e1 = loff[lit + 1];
    float4 s = make_float4(0.f, 0.f, 0.f, 0.f);
    for (int e = e0; e < e1; ++e) {
        const float4 v = *(const float4*)&C[(size_t)litc[e] * F + f4 * 4];
        s.x += v.x; s.y += v.y; s.z += v.z; s.w += v.w;
    }
    float sc = scale[0];
    float cnt = (float)(e1 - e0);
    float r[4] = {s.x, s.y, s.z, s.w};
    float4 o;
#pragma unroll
    for (int j = 0; j < 4; ++j) {
        int col = f4 * 4 + j;
        float m = statsC[col], rs = statsC[80 + col];
        r[j] = (r[j] - cnt * m) * rs * sc;
    }
    o.x = r[0]; o.y = r[1]; o.z = r[2]; o.w = r[3];
    *(float4*)&CL[(size_t)lit * F + f4 * 4] = o;
}

// =====================================================================
// FUSED 2-layer MLP: Out = (relu6(A @ W1 + b1)) @ W2 + b2   (N2 = 80)
// Barrier-free main loop (Hs rows wave-private; A/W frags per-lane from
// global) + REGISTER PREFETCH of the next K-step's A raw values issued
// before the MFMA cluster (HBM latency hides under ~1100cy of MFMA).
// Values and op order identical to rounds 11/14/15.
// =====================================================================
__global__ __launch_bounds__(256, 2)
void mlp_fused(const float* __restrict__ A0, const float* __restrict__ A1,
               const float* __restrict__ A2, int pw, int flip2, int rbase,
               int M, int K1, int N1,
               const us* __restrict__ W1h, const us* __restrict__ W1l,
               const float* __restrict__ b1,
               const us* __restrict__ W2h, const us* __restrict__ W2l,
               const float* __restrict__ b2,
               float* __restrict__ Out, const float* __restrict__ nstat,
               float* __restrict__ Psum, float* __restrict__ Psq) {
    __shared__ __align__(16) us HsH[FBM * LDH];
    __shared__ __align__(16) us HsL[FBM * LDH];
    __shared__ float ns[160];
    __shared__ float bs1[240];
    __shared__ float csum[80], csq[80];

    const int t = threadIdx.x;
    const int m0 = blockIdx.x * FBM;
    const int w = t >> 6;
    const int l = t & 63;
    const int lr = l & 15;
    const int lk = (l >> 4) * 8;

    if (nstat && t < 160) ns[t] = nstat[t];
    if (t < N1) bs1[t] = b1[t];
    if (t < 80) { csum[t] = 0.f; csq[t] = 0.f; }
    for (int u = t; u < FBM * 4; u += 256) {
        int row = u >> 2, cq = u & 3;
        us4 z = {0, 0, 0, 0};
        *(us4*)&HsH[row * LDH + CH + cq * 4] = z;
        *(us4*)&HsL[row * LDH + CH + cq * 4] = z;
    }
    __syncthreads();

    f4v acc2[2][5];
#pragma unroll
    for (int i = 0; i < 2; ++i)
#pragma unroll
        for (int j = 0; j < 5; ++j) acc2[i][j] = (f4v)0.f;

    const int nk1 = (K1 + TBK - 1) / TBK;
    float4 pa[2][2];   // prefetched raw A (normalized at load time)

#define ALOADRAW(S)                                                            \
    {                                                                          \
        int kg_ = (S) * TBK + lk;                                              \
        bool kv_ = kg_ < K1;                                                   \
        _Pragma("unroll")                                                      \
        for (int mf = 0; mf < 2; ++mf) {                                       \
            float4 z = make_float4(0.f, 0.f, 0.f, 0.f);                        \
            pa[mf][0] = z; pa[mf][1] = z;                                      \
            int row = m0 + w * 32 + mf * 16 + lr;                              \
            if (kv_ && row < M) {                                              \
                int piece = (kg_ >= pw) + (kg_ >= 2 * pw);                     \
                int kk = kg_ - piece * pw;                                     \
                const float* P = piece == 0 ? A0 : piece == 1 ? A1 : A2;       \
                int re = row;                                                  \
                if (piece == 2 && flip2) {                                     \
                    int g = rbase + row;                                       \
                    re = (g < NV) ? g + NV : g - NV;                           \
                }                                                              \
                const float* src = P + (size_t)re * pw + kk;                   \
                pa[mf][0] = *(const float4*)src;                               \
                pa[mf][1] = *(const float4*)(src + 4);                         \
                if (piece == 0 && nstat) {                                     \
                    float* pf = (float*)&pa[mf][0];                            \
                    _Pragma("unroll")                                          \
                    for (int j = 0; j < 8; ++j)                                \
                        pf[j] = (pf[j] - ns[kk + j]) * ns[80 + kk + j];        \
                }                                                              \
            }                                                                  \
        }                                                                      \
    }

    for (int c2 = 0; c2 < N1; c2 += CH) {
        // ---------- stage 1: H chunk [FBM x 80], swapped-operand MFMA ----------
        f4v acc1[5][2];   // [n1-frag][m-frag]
#pragma unroll
        for (int i = 0; i < 5; ++i)
#pragma unroll
            for (int j = 0; j < 2; ++j) acc1[i][j] = (f4v)0.f;

        ALOADRAW(0);
        for (int s = 0; s < nk1; ++s) {
            const int kg = s * TBK + lk;
            const bool kv = kg < K1;

            // convert prefetched raw -> bf16 hi/lo fragments
            s8v aH[2], aL[2];
#pragma unroll
            for (int mf = 0; mf < 2; ++mf) {
                float f0[8] = {pa[mf][0].x, pa[mf][0].y, pa[mf][0].z, pa[mf][0].w,
                               pa[mf][1].x, pa[mf][1].y, pa[mf][1].z, pa[mf][1].w};
                s8v h8, l8;
#pragma unroll
                for (int j = 0; j < 8; ++j) {
                    us h = bf16_hi(f0[j]);
                    h8[j] = (short)h;
                    l8[j] = (short)bf16_hi(f0[j] - b2f(h));
                }
                aH[mf] = h8; aL[mf] = l8;
            }
            // W1 fragments: per-lane direct global (L2-hot)
            s8v wH[5], wL[5];
#pragma unroll
            for (int nf = 0; nf < 5; ++nf) {
                int br = c2 + nf * 16 + lr;
                s8v z = {0, 0, 0, 0, 0, 0, 0, 0};
                wH[nf] = kv ? *(const s8v*)&W1h[(size_t)br * K1 + kg] : z;
                wL[nf] = kv ? *(const s8v*)&W1l[(size_t)br * K1 + kg] : z;
            }
            if (s + 1 < nk1) ALOADRAW(s + 1);   // prefetch spans the MFMA cluster
            // swapped operands: W-frag first (-> D row = n1), A-frag second (-> D col = m)
#pragma unroll
            for (int nf = 0; nf < 5; ++nf)
#pragma unroll
                for (int mf = 0; mf < 2; ++mf) {
                    acc1[nf][mf] = __builtin_amdgcn_mfma_f32_16x16x32_bf16(wH[nf], aH[mf], acc1[nf][mf], 0, 0, 0);
                    acc1[nf][mf] = __builtin_amdgcn_mfma_f32_16x16x32_bf16(wL[nf], aH[mf], acc1[nf][mf], 0, 0, 0);
                    acc1[nf][mf] = __builtin_amdgcn_mfma_f32_16x16x32_bf16(wH[nf], aL[mf], acc1[nf][mf], 0, 0, 0);
                }
        }

        // ---------- stage-1 epilogue: bias1 + relu6, split, pack -> wave-private Hs ----
#pragma unroll
        for (int nf = 0; nf < 5; ++nf) {
            int n1b = nf * 16 + ((l >> 4) << 2);
#pragma unroll
            for (int mf = 0; mf < 2; ++mf) {
                int m = w * 32 + mf * 16 + lr;
                us4 hv, lv;
#pragma unroll
                for (int r = 0; r < 4; ++r) {
                    float v = acc1[nf][mf][r] + bs1[c2 + n1b + r];
                    v = fminf(fmaxf(v, 0.f), 6.f);
                    us h = bf16_hi(v);
                    hv[r] = h;
                    lv[r] = bf16_hi(v - b2f(h));
                }
                *(us4*)&HsH[m * LDH + n1b] = hv;
                *(us4*)&HsL[m * LDH + n1b] = lv;
            }
        }
        // no barrier: Hs rows are wave-private (same-wave LDS ordering)

        // ---------- stage 2: acc2 += H_chunk @ W2[c2..c2+80, :] ----------
#pragma unroll
        for (int ks = 0; ks < 3; ++ks) {
            int klocal = ks * 32 + lk;
            s8v a2H[2], a2L[2], b2H[5], b2L[5];
#pragma unroll
            for (int mf = 0; mf < 2; ++mf) {
                int ar = w * 32 + mf * 16 + lr;
                a2H[mf] = *(const s8v*)&HsH[ar * LDH + klocal];
                a2L[mf] = *(const s8v*)&HsL[ar * LDH + klocal];
            }
            bool bval = klocal < CH;
            int kg = c2 + klocal;
#pragma unroll
            for (int nf = 0; nf < 5; ++nf) {
                int n2 = nf * 16 + lr;
                s8v z = {0, 0, 0, 0, 0, 0, 0, 0};
                b2H[nf] = bval ? *(const s8v*)&W2h[(size_t)n2 * N1 + kg] : z;
                b2L[nf] = bval ? *(const s8v*)&W2l[(size_t)n2 * N1 + kg] : z;
            }
#pragma unroll
            for (int mf = 0; mf < 2; ++mf)
#pragma unroll
                for (int nf = 0; nf < 5; ++nf) {
                    acc2[mf][nf] = __builtin_amdgcn_mfma_f32_16x16x32_bf16(a2H[mf], b2H[nf], acc2[mf][nf], 0, 0, 0);
                    acc2[mf][nf] = __builtin_amdgcn_mfma_f32_16x16x32_bf16(a2L[mf], b2H[nf], acc2[mf][nf], 0, 0, 0);
                    acc2[mf][nf] = __builtin_amdgcn_mfma_f32_16x16x32_bf16(a2H[mf], b2L[nf], acc2[mf][nf], 0, 0, 0);
                }
        }
        // no barrier: next chunk overwrites only this wave's own Hs rows
    }
#undef ALOADRAW

    // ---------- final epilogue: bias2, store, fused column stats ----------
#pragma unroll
    for (int nf = 0; nf < 5; ++nf) {
        int col = nf * 16 + lr;
        float bv = b2[col];
        float ls = 0.f, lq = 0.f;
#pragma unroll
        for (int mf = 0; mf < 2; ++mf) {
            int rowb = m0 + w * 32 + mf * 16 + (l >> 4) * 4;
#pragma unroll
            for (int r = 0; r < 4; ++r) {
                int row = rowb + r;
                if (row < M) {
                    float v = acc2[mf][nf][r] + bv;
                    Out[(size_t)row * 80 + col] = v;
                    ls += v; lq += v * v;
                }
            }
        }
        ls += __shfl_xor(ls, 16); ls += __shfl_xor(ls, 32);
        lq += __shfl_xor(lq, 16); lq += __shfl_xor(lq, 32);
        if (l < 16) {
            atomicAdd(&csum[col], ls);
            atomicAdd(&csq[col], lq);
        }
    }
    __syncthreads();
    if (t < 80) {
        size_t pb = (size_t)blockIdx.x * 80 + t;
        Psum[pb] = csum[t];
        Psq[pb] = csq[t];
    }
}

// ---------------- unfused MFMA GEMM (V-MLP) ----------------
__global__ __launch_bounds__(256, 3)
void gemm_mfma(const float* __restrict__ A0, const float* __restrict__ A1,
               const float* __restrict__ A2, int pw, int flip2, int rbase,
               int M, int K, int N,
               const us* __restrict__ Wh, const us* __restrict__ Wl,
               const float* __restrict__ bias, float* __restrict__ Out, int act) {
    __shared__ __align__(16) us AsH[TBM * LDA];
    __shared__ __align__(16) us AsL[TBM * LDA];
    __shared__ __align__(16) us BsH[TBN * LDA];
    __shared__ __align__(16) us BsL[TBN * LDA];

    const int t = threadIdx.x;
    const int m0 = blockIdx.x * TBM;
    const int n0 = blockIdx.y * TBN;
    const int w = t >> 6;
    const int l = t & 63;
    const int lr = l & 15;
    const int lk = (l >> 4) * 8;
    const int q = t & 3;
    const int rb = t >> 2;

    f4v acc[3][5];
#pragma unroll
    for (int i = 0; i < 3; ++i)
#pragma unroll
        for (int j = 0; j < 5; ++j) acc[i][j] = (f4v)0.f;

    float4 pa[3][2];

#define ALOAD(K0)                                                              \
    {                                                                          \
        _Pragma("unroll")                                                      \
        for (int i = 0; i < 3; ++i) {                                          \
            int row = m0 + i * 64 + rb;                                        \
            int kg = (K0) + q * 8;                                             \
            float4 z = make_float4(0.f, 0.f, 0.f, 0.f);                        \
            pa[i][0] = z; pa[i][1] = z;                                        \
            if (row < M && kg < K) {                                           \
                int piece = (kg >= pw) + (kg >= 2 * pw);                       \
                int kk = kg - piece * pw;                                      \
                const float* P = piece == 0 ? A0 : piece == 1 ? A1 : A2;       \
                int re = row;                                                  \
                if (piece == 2 && flip2) {                                     \
                    int g = rbase + row;                                       \
                    re = (g < NV) ? g + NV : g - NV;                           \
                }                                                              \
                const float* src = P + (size_t)re * pw + kk;                   \
                pa[i][0] = *(const float4*)src;                                \
                pa[i][1] = *(const float4*)(src + 4);                          \
            }                                                                  \
        }                                                                      \
    }

    const int nk = (K + TBK - 1) / TBK;
    ALOAD(0);

    for (int s = 0; s < nk; ++s) {
        const int k0 = s * TBK;
#pragma unroll
        for (int i = 0; i < 3; ++i) {
            float f0[8] = {pa[i][0].x, pa[i][0].y, pa[i][0].z, pa[i][0].w,
                           pa[i][1].x, pa[i][1].y, pa[i][1].z, pa[i][1].w};
            us8 hv, lv;
#pragma unroll
            for (int j = 0; j < 8; ++j) {
                us h = bf16_hi(f0[j]);
                hv[j] = h;
                lv[j] = bf16_hi(f0[j] - b2f(h));
            }
            int r = i * 64 + rb;
            *(us8*)&AsH[r * LDA + q * 8] = hv;
            *(us8*)&AsL[r * LDA + q * 8] = lv;
        }
#pragma unroll
        for (int i = 0; i < 3; ++i) {
            int u = i * 256 + t;
            if (u < 640) {
                int hi = (u < 320);
                int c = hi ? u : u - 320;
                int n = c >> 2, cq = c & 3;
                int kg = k0 + cq * 8;
                us8 v = {0, 0, 0, 0, 0, 0, 0, 0};
                if (kg < K)
                    v = *(const us8*)&(hi ? Wh : Wl)[(size_t)(n0 + n) * K + kg];
                *(us8*)&(hi ? BsH : BsL)[n * LDA + cq * 8] = v;
            }
        }
        __syncthreads();

        s8v aH[3], aL[3], bH[5], bL[5];
#pragma unroll
        for (int mf = 0; mf < 3; ++mf) {
            int ar = w * 48 + mf * 16 + lr;
            aH[mf] = *(const s8v*)&AsH[ar * LDA + lk];
            aL[mf] = *(const s8v*)&AsL[ar * LDA + lk];
        }
#pragma unroll
        for (int nf = 0; nf < 5; ++nf) {
            int br = nf * 16 + lr;
            bH[nf] = *(const s8v*)&BsH[br * LDA + lk];
            bL[nf] = *(const s8v*)&BsL[br * LDA + lk];
        }
        if (s + 1 < nk) ALOAD(k0 + TBK);
#pragma unroll
        for (int mf = 0; mf < 3; ++mf)
#pragma unroll
            for (int nf = 0; nf < 5; ++nf) {
                acc[mf][nf] = __builtin_amdgcn_mfma_f32_16x16x32_bf16(aH[mf], bH[nf], acc[mf][nf], 0, 0, 0);
                acc[mf][nf] = __builtin_amdgcn_mfma_f32_16x16x32_bf16(aL[mf], bH[nf], acc[mf][nf], 0, 0, 0);
                acc[mf][nf] = __builtin_amdgcn_mfma_f32_16x16x32_bf16(aH[mf], bL[nf], acc[mf][nf], 0, 0, 0);
            }
        __syncthreads();
    }
#undef ALOAD

#pragma unroll
    for (int mf = 0; mf < 3; ++mf) {
        int rowb = m0 + w * 48 + mf * 16 + (l >> 4) * 4;
#pragma unroll
        for (int nf = 0; nf < 5; ++nf) {
            int col = n0 + nf * 16 + lr;
            float bv = bias[col];
#pragma unroll
            for (int r = 0; r < 4; ++r) {
                int row = rowb + r;
                if (row < M) {
                    float v = acc[mf][nf][r] + bv;
                    if (act) v = fminf(fmaxf(v, 0.f), 6.f);
                    Out[(size_t)row * N + col] = v;
                }
            }
        }
    }
}

// ---------------- stats finalize: one block per column ----------------
__global__ __launch_bounds__(256)
void colstats_final(const float* __restrict__ Psum, const float* __restrict__ Psq,
                    int nblk, int M, float* __restrict__ stats) {
    __shared__ float sd[256], qd[256];
    int c = blockIdx.x;
    int tid = threadIdx.x;
    float s = 0.f, q = 0.f;
    for (int b = tid; b < nblk; b += 256) {
        s += Psum[(size_t)b * 80 + c];
        q += Psq [(size_t)b * 80 + c];
    }
    sd[tid] = s; qd[tid] = q;
    __syncthreads();
    for (int k = 128; k; k >>= 1) {
        if (tid < k) { sd[tid] += sd[tid + k]; qd[tid] += qd[tid + k]; }
        __syncthreads();
    }
    if (tid == 0) {
        float mean = sd[0] / (float)M;
        float var = qd[0] / (float)M - mean * mean;
        if (var < 0.f) var = 0.f;
        stats[c] = mean;
        stats[80 + c] = rsqrtf(var + 1e-3f);
    }
}

__global__ void norm_apply(float* __restrict__ X, int M, const float* __restrict__ stats) {
    int idx = blockIdx.x * 256 + threadIdx.x;
    if (idx >= M * F) return;
    int c = idx % F;
    X[idx] = (X[idx] - stats[c]) * stats[80 + c];
}

// ---------------- final V layer ----------------
__global__ __launch_bounds__(256)
void vscore_kernel(const float* __restrict__ H, const float* __restrict__ w,
                   const float* __restrict__ b, float* __restrict__ out, int M) {
    int wid = (blockIdx.x * 256 + threadIdx.x) / 64;
    int lane = threadIdx.x % 64;
    if (wid >= M) return;
    const float* row = H + (size_t)wid * 160;
    float s = 0.f;
    for (int c = lane; c < 160; c += 64) s += row[c] * w[c];
    for (int off = 32; off; off >>= 1) s += __shfl_down(s, off);
    if (lane == 0) out[wid] = s + b[0];
}

// ---------------- loss ----------------
__global__ __launch_bounds__(256)
void loss_clause(const int* __restrict__ el, const int* __restrict__ off,
                 const float* __restrict__ scores, float* __restrict__ partial, int nc) {
    __shared__ float sd[256];
    int c = blockIdx.x * 256 + threadIdx.x;
    float term = 0.f;
    if (c < nc) {
        int e0 = off[c], e1 = off[c + 1];
        float cs = 0.f;
        for (int e = e0; e < e1; ++e) {
            int lit = el[e];
            float v = (lit < NV) ? scores[lit] : -scores[lit - NV];
            cs += fmaxf(v, 0.f) + log1pf(expf(-fabsf(v)));
        }
        float cv = expf(-cs);
        term = cv * (-logf(1.0f - cv + 1e-8f));
    }
    sd[threadIdx.x] = term;
    __syncthreads();
    for (int s = 128; s; s >>= 1) {
        if (threadIdx.x < s) sd[threadIdx.x] += sd[threadIdx.x + s];
        __syncthreads();
    }
    if (threadIdx.x == 0) partial[blockIdx.x] = sd[0];
}

__global__ void loss_final(const float* __restrict__ partial, int n, float* __restrict__ out) {
    __shared__ float sd[256];
    float s = 0.f;
    for (int i = threadIdx.x; i < n; i += 256) s += partial[i];
    sd[threadIdx.x] = s;
    __syncthreads();
    for (int k = 128; k; k >>= 1) {
        if (threadIdx.x < k) sd[threadIdx.x] += sd[threadIdx.x + k];
        __syncthreads();
    }
    if (threadIdx.x == 0) out[0] = sd[0];
}

// =======================================================================
static inline size_t alignup(size_t x) { return (x + 255) & ~(size_t)255; }

extern "C" void kernel_launch(void* const* d_in, const int* in_sizes, int n_in,
                              void* d_out, int out_size, void* d_ws, size_t ws_size,
                              hipStream_t stream) {
    const int*   el   = (const int*)d_in[0];
    const int*   ec   = (const int*)d_in[1];
    const float* l_init = (const float*)d_in[4];
    const float* c_init = (const float*)d_in[5];
    const float* lc_s = (const float*)d_in[6];
    const float* cl_s = (const float*)d_in[7];
    const float* Cw1 = (const float*)d_in[8],  *Cb1 = (const float*)d_in[9];
    const float* Cw2 = (const float*)d_in[10], *Cb2 = (const float*)d_in[11];
    const float* Lw1 = (const float*)d_in[12], *Lb1 = (const float*)d_in[13];
    const float* Lw2 = (const float*)d_in[14], *Lb2 = (const float*)d_in[15];
    const float* Vw1 = (const float*)d_in[16], *Vb1 = (const float*)d_in[17];
    const float* Vw2 = (const float*)d_in[18], *Vb2 = (const float*)d_in[19];
    const float* Vw3 = (const float*)d_in[20], *Vb3 = (const float*)d_in[21];
    const float* Vw4 = (const float*)d_in[22], *Vb4 = (const float*)d_in[23];
    float* out = (float*)d_out;

    // ---- workspace carve-up ----
    char* p = (char*)d_ws;
    size_t o = 0;
    int* off  = (int*)(p + o); o += alignup((size_t)(NC + 1) * 4);
    int* loff = (int*)(p + o); o += alignup((size_t)(NL + 1) * 4);
    int* lcnt = (int*)(p + o); o += alignup((size_t)NL * 4);
    int* lcur = (int*)(p + o); o += alignup((size_t)NL * 4);
    int* bsum = (int*)(p + o); o += alignup((size_t)512 * 4);
    int* litc = (int*)(p + o); o += alignup((size_t)NNZE * 4);
    float* L0  = (float*)(p + o); o += alignup((size_t)NL * F * 4);
    float* L1  = (float*)(p + o); o += alignup((size_t)NL * F * 4);
    float* Cb  = (float*)(p + o); o += alignup((size_t)NC * F * 4);
    float* MSG = (float*)(p + o); o += alignup((size_t)NC * F * 4);
    float* H   = (float*)(p + o); o += alignup((size_t)8400000 * 4);
    float* Psum = (float*)(p + o); o += alignup((size_t)2048 * 80 * 4);
    float* Psq  = (float*)(p + o); o += alignup((size_t)2048 * 80 * 4);
    float* statsC = (float*)(p + o); o += alignup(160 * 4);
    float* statsL = (float*)(p + o); o += alignup(160 * 4);
    float* lossP  = (float*)(p + o); o += alignup(1024 * 4);
    us* Wsp = (us*)(p + o); o += alignup((size_t)192000 * 2 * 2);
    us* Cw1h = Wsp,          *Cw1l = Cw1h + 25600;
    us* Cw2h = Cw1l + 25600, *Cw2l = Cw2h + 12800;
    us* Lw1h = Cw2l + 12800, *Lw1l = Lw1h + 57600;
    us* Lw2h = Lw1l + 57600, *Lw2l = Lw2h + 19200;
    us* Vw1h = Lw2l + 19200, *Vw1l = Vw1h + 25600;
    us* Vw2h = Vw1l + 25600, *Vw2l = Vw2h + 25600;
    us* Vw3h = Vw2l + 25600, *Vw3l = Vw3h + 25600;
    (void)ws_size; (void)n_in; (void)in_sizes; (void)out_size;

    // ---- CSR offsets + lit-CSR (parallel scan) ----
    build_off<<<(NNZE + 255) / 256, 256, 0, stream>>>(ec, off, NNZE, NC);
    zero_int<<<(NL + 255) / 256, 256, 0, stream>>>(lcnt, NL);
    zero_int<<<(NL + 255) / 256, 256, 0, stream>>>(lcur, NL);
    hist_lit<<<(NNZE + 255) / 256, 256, 0, stream>>>(el, lcnt);
    const int nb = (NL + 255) / 256;   // 391
    scan1<<<nb, 256, 0, stream>>>(lcnt, bsum, NL);
    scan2<<<1, 512, 0, stream>>>(bsum, nb);
    scan3<<<nb, 256, 0, stream>>>(lcnt, bsum, loff, NL);
    scatter_lit<<<(NNZE + 255) / 256, 256, 0, stream>>>(el, ec, loff, lcur, litc);
    seg_sort<<<(NL + 255) / 256, 256, 0, stream>>>(loff, litc);

    // ---- weight pre-split ----
    split_w<<<(25600 + 255) / 256, 256, 0, stream>>>(Cw1, 160, 160, Cw1h, Cw1l);
    split_w<<<(12800 + 255) / 256, 256, 0, stream>>>(Cw2, 160,  80, Cw2h, Cw2l);
    split_w<<<(57600 + 255) / 256, 256, 0, stream>>>(Lw1, 240, 240, Lw1h, Lw1l);
    split_w<<<(19200 + 255) / 256, 256, 0, stream>>>(Lw2, 240,  80, Lw2h, Lw2l);
    split_w<<<(25600 + 255) / 256, 256, 0, stream>>>(Vw1, 160, 160, Vw1h, Vw1l);
    split_w<<<(25600 + 255) / 256, 256, 0, stream>>>(Vw2, 160, 160, Vw2h, Vw2l);
    split_w<<<(25600 + 255) / 256, 256, 0, stream>>>(Vw3, 160, 160, Vw3h, Vw3l);

    // ---- init L, C (raw) ----
    fill_val<<<(NL * F + 255) / 256, 256, 0, stream>>>(L0, NL * F, l_init);
    fill_val<<<(NC * F + 255) / 256, 256, 0, stream>>>(Cb, NC * F, c_init);

    float* Lc = L0, *Ln = L1;
    const int nblkC = (NC + FBM - 1) / FBM;   // 1641
    const int nblkL = (NL + FBM - 1) / FBM;   // 782

    for (int round = 0; round < 4; ++round) {
        // LC_msgs from normalized L
        float* LC = MSG;
        lc_gather<<<(NC * 20 + 255) / 256, 256, 0, stream>>>(Lc, el, off, lc_s, LC);

        // fused C MLP (in-place on raw Cb; piece-0 norm fused for rounds > 0)
        const float* nsC = (round > 0) ? statsC : nullptr;
        mlp_fused<<<nblkC, 256, 0, stream>>>(Cb, LC, nullptr, 80, 0, 0, NC, 160, 160,
                                             Cw1h, Cw1l, Cb1, Cw2h, Cw2l, Cb2,
                                             Cb, nsC, Psum, Psq);
        colstats_final<<<80, 256, 0, stream>>>(Psum, Psq, nblkC, NC, statsC);

        // CL_msgs from RAW C with fused norm (lit-CSR gather)
        float* CL = MSG;
        cl_gather<<<(NL * 20 + 255) / 256, 256, 0, stream>>>(Cb, loff, litc, cl_s, statsC, CL);

        // fused L MLP (reads normalized Lc incl. flip; writes raw Ln)
        mlp_fused<<<nblkL, 256, 0, stream>>>(Lc, CL, Lc, 80, 1, 0, NL, 240, 240,
                                             Lw1h, Lw1l, Lb1, Lw2h, Lw2l, Lb2,
                                             Ln, nullptr, Psum, Psq);
        colstats_final<<<80, 256, 0, stream>>>(Psum, Psq, nblkL, NL, statsL);
        norm_apply<<<(NL * F + 255) / 256, 256, 0, stream>>>(Ln, NL, statsL);

        float* t = Lc; Lc = Ln; Ln = t;
    }

    // ---- V MLP on normalized L (unfused path) ----
    {
        float* H2 = MSG;
        dim3 g((NV + TBM - 1) / TBM, 2);
        gemm_mfma<<<g, 256, 0, stream>>>(Lc, Lc + (size_t)NV * F, nullptr, 80, 0, 0,
                                         NV, 160, 160, Vw1h, Vw1l, Vb1, H, 1);
        gemm_mfma<<<g, 256, 0, stream>>>(H, nullptr, nullptr, 160, 0, 0,
                                         NV, 160, 160, Vw2h, Vw2l, Vb2, H2, 1);
        gemm_mfma<<<g, 256, 0, stream>>>(H2, nullptr, nullptr, 160, 0, 0,
                                         NV, 160, 160, Vw3h, Vw3l, Vb3, H, 1);
        vscore_kernel<<<(NV * 64 + 255) / 256, 256, 0, stream>>>(H, Vw4, Vb4, out, NV);
    }

    // ---- loss ----
    {
        int nblk = (NC + 255) / 256;
        loss_clause<<<nblk, 256, 0, stream>>>(el, off, out, lossP, NC);
        loss_final<<<1, 256, 0, stream>>>(lossP, nblk, out + NV);
    }
}

// Round 17
// 1769.597 us; speedup vs baseline: 1.0312x; 1.0077x over previous
//
#include <hip/hip_runtime.h>
#include <hip/hip_bf16.h>

#define NV 50000
#define NL 100000
#define NC 210000
#define NNZE 630000
#define F 80

// unfused MFMA GEMM tile (V-MLP)
#define TBM 192
#define TBN 80
#define TBK 32
#define LDA 40   // padded LDS row stride in shorts

// fused MLP tile
#define FBM 128  // 4 waves x 32 rows (2 m-frags); Hs-only LDS ~55KB -> 2 blocks/CU
#define CH 80    // H-column chunk (stage-2 K chunk)
#define LDH 104  // Hs row stride in shorts (208 B, 16B-aligned, ~2-way banks)

typedef unsigned short us;
typedef __attribute__((ext_vector_type(8))) short s8v;
typedef __attribute__((ext_vector_type(4))) float f4v;
typedef __attribute__((ext_vector_type(4))) unsigned short us4;
typedef __attribute__((ext_vector_type(8))) unsigned short us8;

__device__ inline us bf16_hi(float x) {
    return (us)(__builtin_bit_cast(unsigned int, x) >> 16);
}
__device__ inline float b2f(us h) {
    return __builtin_bit_cast(float, (unsigned int)h << 16);
}

// ---------------- offsets from sorted edge_clause ----------------
__global__ void build_off(const int* __restrict__ ec, int* __restrict__ off,
                          int nnz, int nc) {
    int e = blockIdx.x * 256 + threadIdx.x;
    if (e >= nnz) return;
    int c = ec[e];
    if (e == 0) {
        for (int cc = 0; cc <= c; ++cc) off[cc] = 0;
    } else {
        int cp = ec[e - 1];
        for (int cc = cp + 1; cc <= c; ++cc) off[cc] = e;
    }
    if (e == nnz - 1) {
        for (int cc = c + 1; cc <= nc; ++cc) off[cc] = nnz;
    }
}

// ---------------- fills ----------------
__global__ void fill_val(float* __restrict__ p, int n, const float* __restrict__ v) {
    int i = blockIdx.x * 256 + threadIdx.x;
    if (i < n) p[i] = v[0];
}
__global__ void zero_int(int* __restrict__ p, int n) {
    int i = blockIdx.x * 256 + threadIdx.x;
    if (i < n) p[i] = 0;
}

// ---------------- lit-CSR build (hist -> 3-stage scan -> scatter -> sort) ----
__global__ void hist_lit(const int* __restrict__ el, int* __restrict__ cnt) {
    int e = blockIdx.x * 256 + threadIdx.x;
    if (e < NNZE) atomicAdd(&cnt[el[e]], 1);
}

__global__ __launch_bounds__(256)
void scan1(const int* __restrict__ cnt, int* __restrict__ bsum, int n) {
    __shared__ int sd[256];
    int i = blockIdx.x * 256 + threadIdx.x;
    sd[threadIdx.x] = (i < n) ? cnt[i] : 0;
    __syncthreads();
    for (int k = 128; k; k >>= 1) {
        if (threadIdx.x < k) sd[threadIdx.x] += sd[threadIdx.x + k];
        __syncthreads();
    }
    if (threadIdx.x == 0) bsum[blockIdx.x] = sd[0];
}

__global__ __launch_bounds__(512)
void scan2(int* __restrict__ bsum, int nb) {   // inclusive scan, nb <= 512
    __shared__ int sd[512];
    int t = threadIdx.x;
    sd[t] = (t < nb) ? bsum[t] : 0;
    __syncthreads();
    for (int off = 1; off < 512; off <<= 1) {
        int v = (t >= off) ? sd[t - off] : 0;
        __syncthreads();
        sd[t] += v;
        __syncthreads();
    }
    if (t < nb) bsum[t] = sd[t];
}

__global__ __launch_bounds__(256)
void scan3(const int* __restrict__ cnt, const int* __restrict__ bsum,
           int* __restrict__ loff, int n) {
    __shared__ int sd[256];
    int t = threadIdx.x;
    int i = blockIdx.x * 256 + t;
    int v = (i < n) ? cnt[i] : 0;
    sd[t] = v;
    __syncthreads();
    for (int off = 1; off < 256; off <<= 1) {
        int u = (t >= off) ? sd[t - off] : 0;
        __syncthreads();
        sd[t] += u;
        __syncthreads();
    }
    int base = blockIdx.x ? bsum[blockIdx.x - 1] : 0;
    if (i < n) loff[i] = base + sd[t] - v;          // exclusive
    if (i == n - 1) loff[n] = base + sd[t];         // total
}

__global__ void scatter_lit(const int* __restrict__ el, const int* __restrict__ ec,
                            const int* __restrict__ loff, int* __restrict__ cur,
                            int* __restrict__ litc) {
    int e = blockIdx.x * 256 + threadIdx.x;
    if (e >= NNZE) return;
    int l = el[e];
    int pos = loff[l] + atomicAdd(&cur[l], 1);
    litc[pos] = ec[e];
}

// deterministic litc content regardless of atomic ordering
__global__ void seg_sort(const int* __restrict__ loff, int* __restrict__ litc) {
    int l = blockIdx.x * 256 + threadIdx.x;
    if (l >= NL) return;
    int a = loff[l], b = loff[l + 1];
    for (int i = a + 1; i < b; ++i) {
        int key = litc[i];
        int j = i - 1;
        while (j >= a && litc[j] > key) { litc[j + 1] = litc[j]; --j; }
        litc[j + 1] = key;
    }
}

// ---------------- weight pre-split: W[K][N] fp32 -> Wh/Wl[N][K] bf16 ----------------
__global__ void split_w(const float* __restrict__ W, int K, int N,
                        us* __restrict__ Wh, us* __restrict__ Wl) {
    int idx = blockIdx.x * 256 + threadIdx.x;
    if (idx >= K * N) return;
    int k = idx / N, n = idx % N;
    float x = W[idx];
    us h = bf16_hi(x);
    Wh[(size_t)n * K + k] = h;
    Wl[(size_t)n * K + k] = bf16_hi(x - b2f(h));
}

// ---------------- LC gather over RAW L with optional fused affine norm ----------------
// LC[c][col] = lc_s * sum_e (Lraw[lit_e][col] - m)*r = lc_s * r * (sum - cnt*m)
__global__ void lc_gather(const float* __restrict__ L, const int* __restrict__ el,
                          const int* __restrict__ off, const float* __restrict__ scale,
                          const float* __restrict__ nstat, float* __restrict__ LC) {
    int idx = blockIdx.x * 256 + threadIdx.x;
    if (idx >= NC * 20) return;
    int c = idx / 20, f4 = idx % 20;
    int e0 = off[c], e1 = off[c + 1];
    float4 s = make_float4(0.f, 0.f, 0.f, 0.f);
    for (int e = e0; e < e1; ++e) {
        const float4 v = *(const float4*)&L[(size_t)el[e] * F + f4 * 4];
        s.x += v.x; s.y += v.y; s.z += v.z; s.w += v.w;
    }
    float sc = scale[0];
    float r[4] = {s.x, s.y, s.z, s.w};
    if (nstat) {
        float cnt = (float)(e1 - e0);
#pragma unroll
        for (int j = 0; j < 4; ++j) {
            int col = f4 * 4 + j;
            r[j] = (r[j] - cnt * nstat[col]) * nstat[80 + col];
        }
    }
#pragma unroll
    for (int j = 0; j < 4; ++j) r[j] *= sc;
    float4 o; o.x = r[0]; o.y = r[1]; o.z = r[2]; o.w = r[3];
    *(float4*)&LC[(size_t)c * F + f4 * 4] = o;
}

// ---------------- CL gather over RAW C with fused affine normalization --------------
__global__ void cl_gather(const float* __restrict__ C, const int* __restrict__ loff,
                          const int* __restrict__ litc, const float* __restrict__ scale,
                          const float* __restrict__ statsC, float* __restrict__ CL) {
    int idx = blockIdx.x * 256 + threadIdx.x;
    if (idx >= NL * 20) return;
    int lit = idx / 20, f4 = idx % 20;
    int e0 = loff[lit], e1 = loff[lit + 1];
    float4 s = make_float4(0.f, 0.f, 0.f, 0.f);
    for (int e = e0; e < e1; ++e) {
        const float4 v = *(const float4*)&C[(size_t)litc[e] * F + f4 * 4];
        s.x += v.x; s.y += v.y; s.z += v.z; s.w += v.w;
    }
    float sc = scale[0];
    float cnt = (float)(e1 - e0);
    float r[4] = {s.x, s.y, s.z, s.w};
    float4 o;
#pragma unroll
    for (int j = 0; j < 4; ++j) {
        int col = f4 * 4 + j;
        float m = statsC[col], rs = statsC[80 + col];
        r[j] = (r[j] - cnt * m) * rs * sc;
    }
    o.x = r[0]; o.y = r[1]; o.z = r[2]; o.w = r[3];
    *(float4*)&CL[(size_t)lit * F + f4 * 4] = o;
}

// =====================================================================
// FUSED 2-layer MLP: Out = (relu6(A @ W1 + b1)) @ W2 + b2   (N2 = 80)
// Barrier-free main loop + register prefetch (round-16 structure).
// nstat (if non-null) affinely normalizes pieces 0 AND 2 (the state
// operand); piece 1 (message buffer, pre-scaled) untouched.
// =====================================================================
__global__ __launch_bounds__(256, 2)
void mlp_fused(const float* __restrict__ A0, const float* __restrict__ A1,
               const float* __restrict__ A2, int pw, int flip2, int rbase,
               int M, int K1, int N1,
               const us* __restrict__ W1h, const us* __restrict__ W1l,
               const float* __restrict__ b1,
               const us* __restrict__ W2h, const us* __restrict__ W2l,
               const float* __restrict__ b2,
               float* __restrict__ Out, const float* __restrict__ nstat,
               float* __restrict__ Psum, float* __restrict__ Psq) {
    __shared__ __align__(16) us HsH[FBM * LDH];
    __shared__ __align__(16) us HsL[FBM * LDH];
    __shared__ float ns[160];
    __shared__ float bs1[240];
    __shared__ float csum[80], csq[80];

    const int t = threadIdx.x;
    const int m0 = blockIdx.x * FBM;
    const int w = t >> 6;
    const int l = t & 63;
    const int lr = l & 15;
    const int lk = (l >> 4) * 8;

    if (nstat && t < 160) ns[t] = nstat[t];
    if (t < N1) bs1[t] = b1[t];
    if (t < 80) { csum[t] = 0.f; csq[t] = 0.f; }
    for (int u = t; u < FBM * 4; u += 256) {
        int row = u >> 2, cq = u & 3;
        us4 z = {0, 0, 0, 0};
        *(us4*)&HsH[row * LDH + CH + cq * 4] = z;
        *(us4*)&HsL[row * LDH + CH + cq * 4] = z;
    }
    __syncthreads();

    f4v acc2[2][5];
#pragma unroll
    for (int i = 0; i < 2; ++i)
#pragma unroll
        for (int j = 0; j < 5; ++j) acc2[i][j] = (f4v)0.f;

    const int nk1 = (K1 + TBK - 1) / TBK;
    float4 pa[2][2];   // prefetched raw A (normalized at load time)

#define ALOADRAW(S)                                                            \
    {                                                                          \
        int kg_ = (S) * TBK + lk;                                              \
        bool kv_ = kg_ < K1;                                                   \
        _Pragma("unroll")                                                      \
        for (int mf = 0; mf < 2; ++mf) {                                       \
            float4 z = make_float4(0.f, 0.f, 0.f, 0.f);                        \
            pa[mf][0] = z; pa[mf][1] = z;                                      \
            int row = m0 + w * 32 + mf * 16 + lr;                              \
            if (kv_ && row < M) {                                              \
                int piece = (kg_ >= pw) + (kg_ >= 2 * pw);                     \
                int kk = kg_ - piece * pw;                                     \
                const float* P = piece == 0 ? A0 : piece == 1 ? A1 : A2;       \
                int re = row;                                                  \
                if (piece == 2 && flip2) {                                     \
                    int g = rbase + row;                                       \
                    re = (g < NV) ? g + NV : g - NV;                           \
                }                                                              \
                const float* src = P + (size_t)re * pw + kk;                   \
                pa[mf][0] = *(const float4*)src;                               \
                pa[mf][1] = *(const float4*)(src + 4);                         \
                if (piece != 1 && nstat) {                                     \
                    float* pf = (float*)&pa[mf][0];                            \
                    _Pragma("unroll")                                          \
                    for (int j = 0; j < 8; ++j)                                \
                        pf[j] = (pf[j] - ns[kk + j]) * ns[80 + kk + j];        \
                }                                                              \
            }                                                                  \
        }                                                                      \
    }

    for (int c2 = 0; c2 < N1; c2 += CH) {
        // ---------- stage 1: H chunk [FBM x 80], swapped-operand MFMA ----------
        f4v acc1[5][2];   // [n1-frag][m-frag]
#pragma unroll
        for (int i = 0; i < 5; ++i)
#pragma unroll
            for (int j = 0; j < 2; ++j) acc1[i][j] = (f4v)0.f;

        ALOADRAW(0);
        for (int s = 0; s < nk1; ++s) {
            const int kg = s * TBK + lk;
            const bool kv = kg < K1;

            // convert prefetched raw -> bf16 hi/lo fragments
            s8v aH[2], aL[2];
#pragma unroll
            for (int mf = 0; mf < 2; ++mf) {
                float f0[8] = {pa[mf][0].x, pa[mf][0].y, pa[mf][0].z, pa[mf][0].w,
                               pa[mf][1].x, pa[mf][1].y, pa[mf][1].z, pa[mf][1].w};
                s8v h8, l8;
#pragma unroll
                for (int j = 0; j < 8; ++j) {
                    us h = bf16_hi(f0[j]);
                    h8[j] = (short)h;
                    l8[j] = (short)bf16_hi(f0[j] - b2f(h));
                }
                aH[mf] = h8; aL[mf] = l8;
            }
            // W1 fragments: per-lane direct global (L2-hot)
            s8v wH[5], wL[5];
#pragma unroll
            for (int nf = 0; nf < 5; ++nf) {
                int br = c2 + nf * 16 + lr;
                s8v z = {0, 0, 0, 0, 0, 0, 0, 0};
                wH[nf] = kv ? *(const s8v*)&W1h[(size_t)br * K1 + kg] : z;
                wL[nf] = kv ? *(const s8v*)&W1l[(size_t)br * K1 + kg] : z;
            }
            if (s + 1 < nk1) ALOADRAW(s + 1);   // prefetch spans the MFMA cluster
            // swapped operands: W-frag first (-> D row = n1), A-frag second (-> D col = m)
#pragma unroll
            for (int nf = 0; nf < 5; ++nf)
#pragma unroll
                for (int mf = 0; mf < 2; ++mf) {
                    acc1[nf][mf] = __builtin_amdgcn_mfma_f32_16x16x32_bf16(wH[nf], aH[mf], acc1[nf][mf], 0, 0, 0);
                    acc1[nf][mf] = __builtin_amdgcn_mfma_f32_16x16x32_bf16(wL[nf], aH[mf], acc1[nf][mf], 0, 0, 0);
                    acc1[nf][mf] = __builtin_amdgcn_mfma_f32_16x16x32_bf16(wH[nf], aL[mf], acc1[nf][mf], 0, 0, 0);
                }
        }

        // ---------- stage-1 epilogue: bias1 + relu6, split, pack -> wave-private Hs ----
#pragma unroll
        for (int nf = 0; nf < 5; ++nf) {
            int n1b = nf * 16 + ((l >> 4) << 2);
#pragma unroll
            for (int mf = 0; mf < 2; ++mf) {
                int m = w * 32 + mf * 16 + lr;
                us4 hv, lv;
#pragma unroll
                for (int r = 0; r < 4; ++r) {
                    float v = acc1[nf][mf][r] + bs1[c2 + n1b + r];
                    v = fminf(fmaxf(v, 0.f), 6.f);
                    us h = bf16_hi(v);
                    hv[r] = h;
                    lv[r] = bf16_hi(v - b2f(h));
                }
                *(us4*)&HsH[m * LDH + n1b] = hv;
                *(us4*)&HsL[m * LDH + n1b] = lv;
            }
        }
        // no barrier: Hs rows are wave-private (same-wave LDS ordering)

        // ---------- stage 2: acc2 += H_chunk @ W2[c2..c2+80, :] ----------
#pragma unroll
        for (int ks = 0; ks < 3; ++ks) {
            int klocal = ks * 32 + lk;
            s8v a2H[2], a2L[2], b2H[5], b2L[5];
#pragma unroll
            for (int mf = 0; mf < 2; ++mf) {
                int ar = w * 32 + mf * 16 + lr;
                a2H[mf] = *(const s8v*)&HsH[ar * LDH + klocal];
                a2L[mf] = *(const s8v*)&HsL[ar * LDH + klocal];
            }
            bool bval = klocal < CH;
            int kg = c2 + klocal;
#pragma unroll
            for (int nf = 0; nf < 5; ++nf) {
                int n2 = nf * 16 + lr;
                s8v z = {0, 0, 0, 0, 0, 0, 0, 0};
                b2H[nf] = bval ? *(const s8v*)&W2h[(size_t)n2 * N1 + kg] : z;
                b2L[nf] = bval ? *(const s8v*)&W2l[(size_t)n2 * N1 + kg] : z;
            }
#pragma unroll
            for (int mf = 0; mf < 2; ++mf)
#pragma unroll
                for (int nf = 0; nf < 5; ++nf) {
                    acc2[mf][nf] = __builtin_amdgcn_mfma_f32_16x16x32_bf16(a2H[mf], b2H[nf], acc2[mf][nf], 0, 0, 0);
                    acc2[mf][nf] = __builtin_amdgcn_mfma_f32_16x16x32_bf16(a2L[mf], b2H[nf], acc2[mf][nf], 0, 0, 0);
                    acc2[mf][nf] = __builtin_amdgcn_mfma_f32_16x16x32_bf16(a2H[mf], b2L[nf], acc2[mf][nf], 0, 0, 0);
                }
        }
        // no barrier: next chunk overwrites only this wave's own Hs rows
    }
#undef ALOADRAW

    // ---------- final epilogue: bias2, store, fused column stats ----------
#pragma unroll
    for (int nf = 0; nf < 5; ++nf) {
        int col = nf * 16 + lr;
        float bv = b2[col];
        float ls = 0.f, lq = 0.f;
#pragma unroll
        for (int mf = 0; mf < 2; ++mf) {
            int rowb = m0 + w * 32 + mf * 16 + (l >> 4) * 4;
#pragma unroll
            for (int r = 0; r < 4; ++r) {
                int row = rowb + r;
                if (row < M) {
                    float v = acc2[mf][nf][r] + bv;
                    Out[(size_t)row * 80 + col] = v;
                    ls += v; lq += v * v;
                }
            }
        }
        ls += __shfl_xor(ls, 16); ls += __shfl_xor(ls, 32);
        lq += __shfl_xor(lq, 16); lq += __shfl_xor(lq, 32);
        if (l < 16) {
            atomicAdd(&csum[col], ls);
            atomicAdd(&csq[col], lq);
        }
    }
    __syncthreads();
    if (t < 80) {
        size_t pb = (size_t)blockIdx.x * 80 + t;
        Psum[pb] = csum[t];
        Psq[pb] = csq[t];
    }
}

// ---------------- unfused MFMA GEMM (V-MLP); nstat normalizes pieces 0/1 ----------------
__global__ __launch_bounds__(256, 3)
void gemm_mfma(const float* __restrict__ A0, const float* __restrict__ A1,
               const float* __restrict__ A2, int pw, int flip2, int rbase,
               int M, int K, int N,
               const us* __restrict__ Wh, const us* __restrict__ Wl,
               const float* __restrict__ bias, float* __restrict__ Out, int act,
               const float* __restrict__ nstat) {
    __shared__ __align__(16) us AsH[TBM * LDA];
    __shared__ __align__(16) us AsL[TBM * LDA];
    __shared__ __align__(16) us BsH[TBN * LDA];
    __shared__ __align__(16) us BsL[TBN * LDA];
    __shared__ float ns[160];

    const int t = threadIdx.x;
    const int m0 = blockIdx.x * TBM;
    const int n0 = blockIdx.y * TBN;
    const int w = t >> 6;
    const int l = t & 63;
    const int lr = l & 15;
    const int lk = (l >> 4) * 8;
    const int q = t & 3;
    const int rb = t >> 2;

    if (nstat && t < 160) ns[t] = nstat[t];
    __syncthreads();

    f4v acc[3][5];
#pragma unroll
    for (int i = 0; i < 3; ++i)
#pragma unroll
        for (int j = 0; j < 5; ++j) acc[i][j] = (f4v)0.f;

    float4 pa[3][2];

#define ALOAD(K0)                                                              \
    {                                                                          \
        _Pragma("unroll")                                                      \
        for (int i = 0; i < 3; ++i) {                                          \
            int row = m0 + i * 64 + rb;                                        \
            int kg = (K0) + q * 8;                                             \
            float4 z = make_float4(0.f, 0.f, 0.f, 0.f);                        \
            pa[i][0] = z; pa[i][1] = z;                                        \
            if (row < M && kg < K) {                                           \
                int piece = (kg >= pw) + (kg >= 2 * pw);                       \
                int kk = kg - piece * pw;                                      \
                const float* P = piece == 0 ? A0 : piece == 1 ? A1 : A2;       \
                int re = row;                                                  \
                if (piece == 2 && flip2) {                                     \
                    int g = rbase + row;                                       \
                    re = (g < NV) ? g + NV : g - NV;                           \
                }                                                              \
                const float* src = P + (size_t)re * pw + kk;                   \
                pa[i][0] = *(const float4*)src;                                \
                pa[i][1] = *(const float4*)(src + 4);                          \
                if (nstat && piece < 2) {                                      \
                    float* pf = (float*)&pa[i][0];                             \
                    _Pragma("unroll")                                          \
                    for (int j = 0; j < 8; ++j)                                \
                        pf[j] = (pf[j] - ns[kk + j]) * ns[80 + kk + j];        \
                }                                                              \
            }                                                                  \
        }                                                                      \
    }

    const int nk = (K + TBK - 1) / TBK;
    ALOAD(0);

    for (int s = 0; s < nk; ++s) {
        const int k0 = s * TBK;
#pragma unroll
        for (int i = 0; i < 3; ++i) {
            float f0[8] = {pa[i][0].x, pa[i][0].y, pa[i][0].z, pa[i][0].w,
                           pa[i][1].x, pa[i][1].y, pa[i][1].z, pa[i][1].w};
            us8 hv, lv;
#pragma unroll
            for (int j = 0; j < 8; ++j) {
                us h = bf16_hi(f0[j]);
                hv[j] = h;
                lv[j] = bf16_hi(f0[j] - b2f(h));
            }
            int r = i * 64 + rb;
            *(us8*)&AsH[r * LDA + q * 8] = hv;
            *(us8*)&AsL[r * LDA + q * 8] = lv;
        }
#pragma unroll
        for (int i = 0; i < 3; ++i) {
            int u = i * 256 + t;
            if (u < 640) {
                int hi = (u < 320);
                int c = hi ? u : u - 320;
                int n = c >> 2, cq = c & 3;
                int kg = k0 + cq * 8;
                us8 v = {0, 0, 0, 0, 0, 0, 0, 0};
                if (kg < K)
                    v = *(const us8*)&(hi ? Wh : Wl)[(size_t)(n0 + n) * K + kg];
                *(us8*)&(hi ? BsH : BsL)[n * LDA + cq * 8] = v;
            }
        }
        __syncthreads();

        s8v aH[3], aL[3], bH[5], bL[5];
#pragma unroll
        for (int mf = 0; mf < 3; ++mf) {
            int ar = w * 48 + mf * 16 + lr;
            aH[mf] = *(const s8v*)&AsH[ar * LDA + lk];
            aL[mf] = *(const s8v*)&AsL[ar * LDA + lk];
        }
#pragma unroll
        for (int nf = 0; nf < 5; ++nf) {
            int br = nf * 16 + lr;
            bH[nf] = *(const s8v*)&BsH[br * LDA + lk];
            bL[nf] = *(const s8v*)&BsL[br * LDA + lk];
        }
        if (s + 1 < nk) ALOAD(k0 + TBK);
#pragma unroll
        for (int mf = 0; mf < 3; ++mf)
#pragma unroll
            for (int nf = 0; nf < 5; ++nf) {
                acc[mf][nf] = __builtin_amdgcn_mfma_f32_16x16x32_bf16(aH[mf], bH[nf], acc[mf][nf], 0, 0, 0);
                acc[mf][nf] = __builtin_amdgcn_mfma_f32_16x16x32_bf16(aL[mf], bH[nf], acc[mf][nf], 0, 0, 0);
                acc[mf][nf] = __builtin_amdgcn_mfma_f32_16x16x32_bf16(aH[mf], bL[nf], acc[mf][nf], 0, 0, 0);
            }
        __syncthreads();
    }
#undef ALOAD

#pragma unroll
    for (int mf = 0; mf < 3; ++mf) {
        int rowb = m0 + w * 48 + mf * 16 + (l >> 4) * 4;
#pragma unroll
        for (int nf = 0; nf < 5; ++nf) {
            int col = n0 + nf * 16 + lr;
            float bv = bias[col];
#pragma unroll
            for (int r = 0; r < 4; ++r) {
                int row = rowb + r;
                if (row < M) {
                    float v = acc[mf][nf][r] + bv;
                    if (act) v = fminf(fmaxf(v, 0.f), 6.f);
                    Out[(size_t)row * N + col] = v;
                }
            }
        }
    }
}

// ---------------- stats finalize: one block per column ----------------
__global__ __launch_bounds__(256)
void colstats_final(const float* __restrict__ Psum, const float* __restrict__ Psq,
                    int nblk, int M, float* __restrict__ stats) {
    __shared__ float sd[256], qd[256];
    int c = blockIdx.x;
    int tid = threadIdx.x;
    float s = 0.f, q = 0.f;
    for (int b = tid; b < nblk; b += 256) {
        s += Psum[(size_t)b * 80 + c];
        q += Psq [(size_t)b * 80 + c];
    }
    sd[tid] = s; qd[tid] = q;
    __syncthreads();
    for (int k = 128; k; k >>= 1) {
        if (tid < k) { sd[tid] += sd[tid + k]; qd[tid] += qd[tid + k]; }
        __syncthreads();
    }
    if (tid == 0) {
        float mean = sd[0] / (float)M;
        float var = qd[0] / (float)M - mean * mean;
        if (var < 0.f) var = 0.f;
        stats[c] = mean;
        stats[80 + c] = rsqrtf(var + 1e-3f);
    }
}

// ---------------- final V layer ----------------
__global__ __launch_bounds__(256)
void vscore_kernel(const float* __restrict__ H, const float* __restrict__ w,
                   const float* __restrict__ b, float* __restrict__ out, int M) {
    int wid = (blockIdx.x * 256 + threadIdx.x) / 64;
    int lane = threadIdx.x % 64;
    if (wid >= M) return;
    const float* row = H + (size_t)wid * 160;
    float s = 0.f;
    for (int c = lane; c < 160; c += 64) s += row[c] * w[c];
    for (int off = 32; off; off >>= 1) s += __shfl_down(s, off);
    if (lane == 0) out[wid] = s + b[0];
}

// ---------------- loss ----------------
__global__ __launch_bounds__(256)
void loss_clause(const int* __restrict__ el, const int* __restrict__ off,
                 const float* __restrict__ scores, float* __restrict__ partial, int nc) {
    __shared__ float sd[256];
    int c = blockIdx.x * 256 + threadIdx.x;
    float term = 0.f;
    if (c < nc) {
        int e0 = off[c], e1 = off[c + 1];
        float cs = 0.f;
        for (int e = e0; e < e1; ++e) {
            int lit = el[e];
            float v = (lit < NV) ? scores[lit] : -scores[lit - NV];
            cs += fmaxf(v, 0.f) + log1pf(expf(-fabsf(v)));
        }
        float cv = expf(-cs);
        term = cv * (-logf(1.0f - cv + 1e-8f));
    }
    sd[threadIdx.x] = term;
    __syncthreads();
    for (int s = 128; s; s >>= 1) {
        if (threadIdx.x < s) sd[threadIdx.x] += sd[threadIdx.x + s];
        __syncthreads();
    }
    if (threadIdx.x == 0) partial[blockIdx.x] = sd[0];
}

__global__ void loss_final(const float* __restrict__ partial, int n, float* __restrict__ out) {
    __shared__ float sd[256];
    float s = 0.f;
    for (int i = threadIdx.x; i < n; i += 256) s += partial[i];
    sd[threadIdx.x] = s;
    __syncthreads();
    for (int k = 128; k; k >>= 1) {
        if (threadIdx.x < k) sd[threadIdx.x] += sd[threadIdx.x + k];
        __syncthreads();
    }
    if (threadIdx.x == 0) out[0] = sd[0];
}

// =======================================================================
static inline size_t alignup(size_t x) { return (x + 255) & ~(size_t)255; }

extern "C" void kernel_launch(void* const* d_in, const int* in_sizes, int n_in,
                              void* d_out, int out_size, void* d_ws, size_t ws_size,
                              hipStream_t stream) {
    const int*   el   = (const int*)d_in[0];
    const int*   ec   = (const int*)d_in[1];
    const float* l_init = (const float*)d_in[4];
    const float* c_init = (const float*)d_in[5];
    const float* lc_s = (const float*)d_in[6];
    const float* cl_s = (const float*)d_in[7];
    const float* Cw1 = (const float*)d_in[8],  *Cb1 = (const float*)d_in[9];
    const float* Cw2 = (const float*)d_in[10], *Cb2 = (const float*)d_in[11];
    const float* Lw1 = (const float*)d_in[12], *Lb1 = (const float*)d_in[13];
    const float* Lw2 = (const float*)d_in[14], *Lb2 = (const float*)d_in[15];
    const float* Vw1 = (const float*)d_in[16], *Vb1 = (const float*)d_in[17];
    const float* Vw2 = (const float*)d_in[18], *Vb2 = (const float*)d_in[19];
    const float* Vw3 = (const float*)d_in[20], *Vb3 = (const float*)d_in[21];
    const float* Vw4 = (const float*)d_in[22], *Vb4 = (const float*)d_in[23];
    float* out = (float*)d_out;

    // ---- workspace carve-up ----
    char* p = (char*)d_ws;
    size_t o = 0;
    int* off  = (int*)(p + o); o += alignup((size_t)(NC + 1) * 4);
    int* loff = (int*)(p + o); o += alignup((size_t)(NL + 1) * 4);
    int* lcnt = (int*)(p + o); o += alignup((size_t)NL * 4);
    int* lcur = (int*)(p + o); o += alignup((size_t)NL * 4);
    int* bsum = (int*)(p + o); o += alignup((size_t)512 * 4);
    int* litc = (int*)(p + o); o += alignup((size_t)NNZE * 4);
    float* L0  = (float*)(p + o); o += alignup((size_t)NL * F * 4);
    float* L1  = (float*)(p + o); o += alignup((size_t)NL * F * 4);
    float* Cb  = (float*)(p + o); o += alignup((size_t)NC * F * 4);
    float* MSG = (float*)(p + o); o += alignup((size_t)NC * F * 4);
    float* H   = (float*)(p + o); o += alignup((size_t)8400000 * 4);
    float* Psum = (float*)(p + o); o += alignup((size_t)2048 * 80 * 4);
    float* Psq  = (float*)(p + o); o += alignup((size_t)2048 * 80 * 4);
    float* statsC = (float*)(p + o); o += alignup(160 * 4);
    float* statsL = (float*)(p + o); o += alignup(160 * 4);
    float* lossP  = (float*)(p + o); o += alignup(1024 * 4);
    us* Wsp = (us*)(p + o); o += alignup((size_t)192000 * 2 * 2);
    us* Cw1h = Wsp,          *Cw1l = Cw1h + 25600;
    us* Cw2h = Cw1l + 25600, *Cw2l = Cw2h + 12800;
    us* Lw1h = Cw2l + 12800, *Lw1l = Lw1h + 57600;
    us* Lw2h = Lw1l + 57600, *Lw2l = Lw2h + 19200;
    us* Vw1h = Lw2l + 19200, *Vw1l = Vw1h + 25600;
    us* Vw2h = Vw1l + 25600, *Vw2l = Vw2h + 25600;
    us* Vw3h = Vw2l + 25600, *Vw3l = Vw3h + 25600;
    (void)ws_size; (void)n_in; (void)in_sizes; (void)out_size;

    // ---- CSR offsets + lit-CSR (parallel scan) ----
    build_off<<<(NNZE + 255) / 256, 256, 0, stream>>>(ec, off, NNZE, NC);
    zero_int<<<(NL + 255) / 256, 256, 0, stream>>>(lcnt, NL);
    zero_int<<<(NL + 255) / 256, 256, 0, stream>>>(lcur, NL);
    hist_lit<<<(NNZE + 255) / 256, 256, 0, stream>>>(el, lcnt);
    const int nb = (NL + 255) / 256;   // 391
    scan1<<<nb, 256, 0, stream>>>(lcnt, bsum, NL);
    scan2<<<1, 512, 0, stream>>>(bsum, nb);
    scan3<<<nb, 256, 0, stream>>>(lcnt, bsum, loff, NL);
    scatter_lit<<<(NNZE + 255) / 256, 256, 0, stream>>>(el, ec, loff, lcur, litc);
    seg_sort<<<(NL + 255) / 256, 256, 0, stream>>>(loff, litc);

    // ---- weight pre-split ----
    split_w<<<(25600 + 255) / 256, 256, 0, stream>>>(Cw1, 160, 160, Cw1h, Cw1l);
    split_w<<<(12800 + 255) / 256, 256, 0, stream>>>(Cw2, 160,  80, Cw2h, Cw2l);
    split_w<<<(57600 + 255) / 256, 256, 0, stream>>>(Lw1, 240, 240, Lw1h, Lw1l);
    split_w<<<(19200 + 255) / 256, 256, 0, stream>>>(Lw2, 240,  80, Lw2h, Lw2l);
    split_w<<<(25600 + 255) / 256, 256, 0, stream>>>(Vw1, 160, 160, Vw1h, Vw1l);
    split_w<<<(25600 + 255) / 256, 256, 0, stream>>>(Vw2, 160, 160, Vw2h, Vw2l);
    split_w<<<(25600 + 255) / 256, 256, 0, stream>>>(Vw3, 160, 160, Vw3h, Vw3l);

    // ---- init L, C (raw) ----
    fill_val<<<(NL * F + 255) / 256, 256, 0, stream>>>(L0, NL * F, l_init);
    fill_val<<<(NC * F + 255) / 256, 256, 0, stream>>>(Cb, NC * F, c_init);

    float* Lc = L0, *Ln = L1;
    const int nblkC = (NC + FBM - 1) / FBM;   // 1641
    const int nblkL = (NL + FBM - 1) / FBM;   // 782

    for (int round = 0; round < 4; ++round) {
        const float* nsL = (round > 0) ? statsL : nullptr;
        const float* nsC = (round > 0) ? statsC : nullptr;

        // LC_msgs from RAW L with fused norm (rounds > 0)
        float* LC = MSG;
        lc_gather<<<(NC * 20 + 255) / 256, 256, 0, stream>>>(Lc, el, off, lc_s, nsL, LC);

        // fused C MLP (in-place on raw Cb; piece-0 norm fused for rounds > 0)
        mlp_fused<<<nblkC, 256, 0, stream>>>(Cb, LC, nullptr, 80, 0, 0, NC, 160, 160,
                                             Cw1h, Cw1l, Cb1, Cw2h, Cw2l, Cb2,
                                             Cb, nsC, Psum, Psq);
        colstats_final<<<80, 256, 0, stream>>>(Psum, Psq, nblkC, NC, statsC);

        // CL_msgs from RAW C with fused norm (lit-CSR gather)
        float* CL = MSG;
        cl_gather<<<(NL * 20 + 255) / 256, 256, 0, stream>>>(Cb, loff, litc, cl_s, statsC, CL);

        // fused L MLP (raw Lc; pieces 0/2 normalized via nsL; writes raw Ln)
        mlp_fused<<<nblkL, 256, 0, stream>>>(Lc, CL, Lc, 80, 1, 0, NL, 240, 240,
                                             Lw1h, Lw1l, Lb1, Lw2h, Lw2l, Lb2,
                                             Ln, nsL, Psum, Psq);
        colstats_final<<<80, 256, 0, stream>>>(Psum, Psq, nblkL, NL, statsL);

        float* t = Lc; Lc = Ln; Ln = t;
    }

    // ---- V MLP on raw L, layer 1 normalizes via statsL ----
    {
        float* H2 = MSG;
        dim3 g((NV + TBM - 1) / TBM, 2);
        gemm_mfma<<<g, 256, 0, stream>>>(Lc, Lc + (size_t)NV * F, nullptr, 80, 0, 0,
                                         NV, 160, 160, Vw1h, Vw1l, Vb1, H, 1, statsL);
        gemm_mfma<<<g, 256, 0, stream>>>(H, nullptr, nullptr, 160, 0, 0,
                                         NV, 160, 160, Vw2h, Vw2l, Vb2, H2, 1, nullptr);
        gemm_mfma<<<g, 256, 0, stream>>>(H2, nullptr, nullptr, 160, 0, 0,
                                         NV, 160, 160, Vw3h, Vw3l, Vb3, H, 1, nullptr);
        vscore_kernel<<<(NV * 64 + 255) / 256, 256, 0, stream>>>(H, Vw4, Vb4, out, NV);
    }

    // ---- loss ----
    {
        int nblk = (NC + 255) / 256;
        loss_clause<<<nblk, 256, 0, stream>>>(el, off, out, lossP, NC);
        loss_final<<<1, 256, 0, stream>>>(lossP, nblk, out + NV);
    }
}